// Round 8
// baseline (273.866 us; speedup 1.0000x reference)
//
#include <hip/hip_runtime.h>

// ColorGradientNet on MI355X — round 8: kNN distance pass on interleaved [x,y,z,xx] float4.
//  * xyzw_kernel precomputes xx per point ONCE (exact reference op order -> bit-identical
//    distances); knn stages 16KB xyzw tiles, distance j = 1 ds_read_b128 + 9 VALU
//    (was 3 ds_read_b32 + 14 VALU incl. redundant xxm recompute).
//  * LDS/block 26.6->18KB: up to 8 blocks/CU. Selection (threshold+bitonic) unchanged.
// edge / GEMMs / xg path unchanged from round 7.
// Workspace layout (bytes):
//   idx  @ 0          : 32768*20 int32                  = 2,621,440
//   x1   @ 2621440    : 2 planes x 2,097,152 ushort     = 8,388,608
//   x2   @ 11010048   : 2 x 4,194,304 ushort            = 16,777,216
//   x3   @ 27787264   : 2 x 8,388,608 ushort            = 33,554,432
//   w2p  @ 61341696   : 2 x 4,096 ushort (overlays x4p; live [prep,edge])
//   x4p  @ 61341696   : 8*8*256 f32 (live [max,x4])
//   xgf  @ 61407232   : 8*1024 f32 (live [xg,yb])
//   x4f  @ 61440000   : 8*256 f32 (overlays w3fp; live [x4,xg])
//   yb   @ 61448192   : 8*512 f32 (live [yb,l1 gemm])
//   w3f  @ 61440000   : 2 x 8,192 ushort (live [prep, x2 gemm])
//   w4p  @ 61472768   : 2 x 32,768 ushort
//   l2wp @ 61603840   : 2 x 131,072 ushort
//   l1wp @ 62128128   : 2 x 229,376 ushort (l1w tail cols 1024..1471)
//   h5   @ 65142784   : 2 x 16,777,216 ushort
//   xyzw @ 132251648  : 32768 float4                    = 524,288  (end 132,775,936)
//   h6   @ 11010048   : 32768*256 f32 (overlays x2/x3 — dead after l1 gemm)

#define KNN 20
#define NPID 32768
#define RS 0.99999500003750f  // 1/sqrt(1+1e-5)

#define X3_PO 8388608
#define X2_PO 4194304
#define X1_PO 2097152

typedef unsigned short ushort_t;
typedef unsigned int u32;
typedef __attribute__((ext_vector_type(8))) short bf16x8;
typedef __attribute__((ext_vector_type(4))) float f32x4;

#define LDS_PTR(p) ((__attribute__((address_space(3))) void*)(p))
#define GLB_PTR(p) ((const __attribute__((address_space(1))) void*)(p))

__device__ __forceinline__ float lrelu(float z) { return z >= 0.f ? z : 0.2f * z; }
__device__ __forceinline__ unsigned short f2bf(float f) {
  unsigned int u = __float_as_uint(f);
  return (unsigned short)((u + 0x7fffu + ((u >> 16) & 1u)) >> 16);
}
__device__ __forceinline__ float bf2f(unsigned short h) { return __uint_as_float((unsigned int)h << 16); }
__device__ __forceinline__ u32 pack2(u32 e0, u32 e1) { return (e1 << 16) | (e0 & 0xffffu); }
__device__ __forceinline__ f32x4 mfma16(uint4 a, uint4 b, f32x4 c) {
  return __builtin_amdgcn_mfma_f32_16x16x32_bf16(
      __builtin_bit_cast(bf16x8, a), __builtin_bit_cast(bf16x8, b), c, 0, 0, 0);
}

// ---------------- xyzw prep: interleave [x,y,z,xx] per point (exact ref op order) ----------------
__global__ __launch_bounds__(256) void xyzw_kernel(const float* __restrict__ x, float4* __restrict__ xyzw) {
  const int i = blockIdx.x * 256 + threadIdx.x;  // 0..32767
  const int b = i >> 12, n = i & 4095;
  const float* xb = x + (size_t)b * 40960;
  const float px = xb[n], py = xb[4096 + n], pz = xb[8192 + n];
  const float xx = __fadd_rn(__fadd_rn(__fmul_rn(px, px), __fmul_rn(py, py)), __fmul_rn(pz, pz));
  float4 v; v.x = px; v.y = py; v.z = pz; v.w = xx;
  xyzw[i] = v;
}

// ---------------- kNN: xyzw-tiled distances + threshold + bitonic ----------------
// d[] index j -> candidate m = (j>>4)*1024 + (j&15)*64 + lane.
__global__ __launch_bounds__(256) void knn_kernel(const float4* __restrict__ xyzw, int* __restrict__ idxo) {
  __shared__ __align__(16) float4 pt[1024];  // 16KB xyzw tile
  __shared__ float cval[4][64];
  __shared__ int cidx[4][64];
  const int tid = threadIdx.x, lane = tid & 63, wave = tid >> 6;
  const int pid = blockIdx.x * 4 + wave;
  const int b = pid >> 12, n = pid & 4095;
  const float4* xw = xyzw + ((size_t)b << 12);
  const float4 P = xw[n];
  const float px = P.x, py = P.y, pz = P.z, xxn = P.w;
  float d[64];
  float lmax = -3.4e38f;
#pragma unroll                    // FULL unroll: all d[] indices compile-time (rule #20)
  for (int t = 0; t < 4; ++t) {
    if (t) __syncthreads();       // all waves done reading previous tile
#pragma unroll
    for (int r = 0; r < 4; ++r) { // stage 1024 pts x 16B = 16 chunks of 1KB; 4 per wave
      const int chunk = wave * 4 + r;
      const float4* src = xw + t * 1024 + chunk * 64 + lane;
      __builtin_amdgcn_global_load_lds(GLB_PTR(src), LDS_PTR((char*)pt + chunk * 1024), 16, 0, 0);
    }
    __syncthreads();
#pragma unroll
    for (int jj = 0; jj < 16; ++jj) {
      const float4 Q = pt[jj * 64 + lane];
      const float inner = __fadd_rn(__fadd_rn(__fmul_rn(px, Q.x), __fmul_rn(py, Q.y)), __fmul_rn(pz, Q.z));
      const float pd = __fsub_rn(__fsub_rn(__fmul_rn(2.0f, inner), xxn), Q.w);
      d[t * 16 + jj] = pd;
      lmax = fmaxf(lmax, pd);
    }
  }
  // bitonic sort of the 64 lane maxima, descending (value only)
  float v = lmax;
#pragma unroll
  for (int k = 2; k <= 64; k <<= 1) {
#pragma unroll
    for (int j = k >> 1; j > 0; j >>= 1) {
      const float ov = __shfl_xor(v, j, 64);
      const bool keepMax = (((lane & k) == 0) == ((lane & j) == 0));
      v = keepMax ? fmaxf(v, ov) : fminf(v, ov);
    }
  }
  const float t0 = __shfl(v, 19, 64);  // lower bound on true 20th-largest
  // ballot-compact candidates >= t0 (j-major, lane-asc: deterministic)
  int base = 0;
#pragma unroll
  for (int j = 0; j < 64; ++j) {
    const bool take = (d[j] >= t0);
    const unsigned long long mk = __ballot(take);
    if (take) {
      const int pos = base + __popcll(mk & ((1ull << lane) - 1ull));
      if (pos < 64) {
        cval[wave][pos] = d[j];
        cidx[wave][pos] = ((j >> 4) << 10) + ((j & 15) << 6) + lane;
      }
    }
    base += (int)__popcll(mk);
  }
  const int C = base;  // wave-uniform
  int* out = idxo + (size_t)pid * KNN;
  if (C <= 64) {
    unsigned long long key = 0ull;
    if (lane < C) {
      const unsigned int u = __float_as_uint(cval[wave][lane]);
      const unsigned int ou = (u & 0x80000000u) ? ~u : (u | 0x80000000u);
      key = ((unsigned long long)ou << 32) | (unsigned long long)(0xFFFFFFFFu - (unsigned int)cidx[wave][lane]);
    }
#pragma unroll
    for (int k = 2; k <= 64; k <<= 1) {
#pragma unroll
      for (int j = k >> 1; j > 0; j >>= 1) {
        const unsigned long long ok = (unsigned long long)__shfl_xor((long long)key, j, 64);
        const bool keepMax = (((lane & k) == 0) == ((lane & j) == 0));
        const bool gt = key > ok;
        key = (keepMax == gt) ? key : ok;
      }
    }
    if (lane < KNN) out[lane] = (int)(0xFFFFFFFFu - (unsigned int)key);
  } else {
    // exact fallback (statistically never taken)
    unsigned long long used = 0ull;
#pragma unroll 1
    for (int it = 0; it < KNN; ++it) {
      float lv = -3.4e38f;
      int li = 1 << 30;
#pragma unroll
      for (int j = 0; j < 64; ++j) {
        if (!((used >> j) & 1ull) && d[j] > lv) {
          lv = d[j];
          li = ((j >> 4) << 10) + ((j & 15) << 6) + lane;
        }
      }
      float bv = lv;
      int bi = li;
#pragma unroll
      for (int s = 1; s < 64; s <<= 1) {
        const float ovv = __shfl_xor(bv, s, 64);
        const int oii = __shfl_xor(bi, s, 64);
        if (ovv > bv || (ovv == bv && oii < bi)) { bv = ovv; bi = oii; }
      }
      if (lane == 0) out[it] = bi;
      if ((bi & 63) == lane) {
        const int jg = ((bi >> 10) << 4) + ((bi & 1023) >> 6);
        used |= 1ull << jg;
      }
    }
  }
}

// ---------------- edge: fused MFMA h1(9->64) + h2(64->64) + max over k ----------------
__global__ __launch_bounds__(256) void edge_kernel(const float* __restrict__ x, const int* __restrict__ idxi,
    const float* __restrict__ w1, const float* __restrict__ g1, const float* __restrict__ b1,
    const ushort_t* __restrict__ w2p, const float* __restrict__ g2, const float* __restrict__ b2,
    ushort_t* __restrict__ x1o) {
  __shared__ u32 hstage[4][16][64];
  const int tid = threadIdx.x, lane = tid & 63, wave = tid >> 6;
  const int fr = lane & 15, kg = lane >> 4;
  const int pbase = blockIdx.x * 64 + wave * 16;
  const int b = (blockIdx.x * 64) >> 12;
  const float* xq = x + (size_t)b * 40960;

  const int nA = (pbase + fr) & 4095;
  float cv[6]; ushort_t chv[6], clv[6];
#pragma unroll
  for (int j = 0; j < 6; ++j) {
    cv[j] = xq[j * 4096 + nA];
    chv[j] = f2bf(cv[j]);
    clv[j] = f2bf(cv[j] - bf2f(chv[j]));
  }
  const float crv = cv[3], cgv = cv[4], cbv = cv[5];

  u32 aC0 = 0, aC1 = 0, aC2 = 0, aC3 = 0;
  if (kg == 0) { aC0 = pack2(chv[0], chv[1]); aC1 = pack2(chv[2], chv[3]); aC2 = pack2(chv[4], chv[5]); }
  else if (kg == 1) { aC0 = (u32)chv[0] << 16; aC1 = pack2(chv[1], chv[2]); aC2 = pack2(chv[3], chv[4]); aC3 = chv[5]; }
  else if (kg == 2) { aC1 = pack2(clv[0], clv[1]); aC2 = pack2(clv[2], clv[3]); aC3 = pack2(clv[4], clv[5]); }

  float s1v[4], t1v[4], s2v[4], t2v[4];
#pragma unroll
  for (int fj = 0; fj < 4; ++fj) {
    const int och = fj * 16 + fr;
    s1v[fj] = g1[och] * RS; t1v[fj] = b1[och];
    s2v[fj] = g2[och] * RS; t2v[fj] = b2[och];
  }

  uint4 w1Bv[4];
#pragma unroll
  for (int fj = 0; fj < 4; ++fj) {
    const int och = fj * 16 + fr;
    ushort_t wh[9], wl[9];
#pragma unroll
    for (int j = 0; j < 9; ++j) {
      const float wv = w1[och * 9 + j];
      wh[j] = f2bf(wv);
      wl[j] = f2bf(wv - bf2f(wh[j]));
    }
    uint4 q;
    if (kg == 0)      { q.x = pack2(wh[0], wh[1]); q.y = pack2(wh[2], wh[3]); q.z = pack2(wh[4], wh[5]); q.w = pack2(wh[6], wh[7]); }
    else if (kg == 1) { q.x = pack2(wh[8], wl[0]); q.y = pack2(wl[1], wl[2]); q.z = pack2(wl[3], wl[4]); q.w = pack2(wl[5], wl[6]); }
    else if (kg == 2) { q.x = pack2(wl[7], wl[8]); q.y = pack2(wh[0], wh[1]); q.z = pack2(wh[2], wh[3]); q.w = pack2(wh[4], wh[5]); }
    else              { q.x = pack2(wh[6], wh[7]); q.y = pack2(wh[8], 0);     q.z = 0;                   q.w = 0; }
    w1Bv[fj] = q;
  }

  uint4 w2Bh[4][2], w2Bl[4][2];
#pragma unroll
  for (int fj = 0; fj < 4; ++fj) {
    const int och = fj * 16 + fr;
#pragma unroll
    for (int sub = 0; sub < 2; ++sub) {
      const ushort_t* ph = w2p + och * 64 + sub * 32 + kg * 8;
      w2Bh[fj][sub] = *(const uint4*)ph;
      w2Bl[fj][sub] = *(const uint4*)(ph + 4096);
    }
  }

  const int prow = (pbase + fr) * KNN;
  int miA = idxi[prow];
  int miN = idxi[prow + 1];
  float pr = xq[12288 + miA], pg = xq[16384 + miA], pb = xq[20480 + miA];

  f32x4 xm[4];
#pragma unroll
  for (int fj = 0; fj < 4; ++fj) { xm[fj][0] = -3.4e38f; xm[fj][1] = -3.4e38f; xm[fj][2] = -3.4e38f; xm[fj][3] = -3.4e38f; }
  const f32x4 zz = {0.f, 0.f, 0.f, 0.f};

#pragma unroll 1
  for (int kk = 0; kk < KNN; ++kk) {
    const float nrv = pr, ngv = pg, nbv = pb;
    if (kk < KNN - 1) { pr = xq[12288 + miN]; pg = xq[16384 + miN]; pb = xq[20480 + miN]; }
    if (kk < KNN - 2) { miN = idxi[prow + kk + 2]; }

    const float dr = crv - nrv, dg = cgv - ngv, db = cbv - nbv;
    const ushort_t drh = f2bf(dr), dgh = f2bf(dg), dbh = f2bf(db);
    const ushort_t drl = f2bf(dr - bf2f(drh)), dgl = f2bf(dg - bf2f(dgh)), dbl = f2bf(db - bf2f(dbh));

    uint4 aF;
    if (kg == 0)      { aF.x = aC0; aF.y = aC1; aF.z = aC2; aF.w = pack2(drh, dgh); }
    else if (kg == 1) { aF.x = aC0 | dbh; aF.y = aC1; aF.z = aC2; aF.w = aC3 | ((u32)drh << 16); }
    else if (kg == 2) { aF.x = pack2(dgh, dbh); aF.y = aC1; aF.z = aC2; aF.w = aC3; }
    else              { aF.x = pack2(drl, dgl); aF.y = (u32)dbl; aF.z = 0; aF.w = 0; }

    f32x4 h1a[4];
#pragma unroll
    for (int fj = 0; fj < 4; ++fj) h1a[fj] = mfma16(aF, w1Bv[fj], zz);

#pragma unroll
    for (int fj = 0; fj < 4; ++fj)
#pragma unroll
      for (int r = 0; r < 4; ++r) {
        float z = h1a[fj][r] * s1v[fj] + t1v[fj];
        z = fmaxf(z, 0.2f * z);
        const ushort_t hi = f2bf(z), lo = f2bf(z - bf2f(hi));
        const int pC = kg * 4 + r;
        hstage[wave][pC][(fj * 16 + fr) ^ ((pC & 7) << 3)] = ((u32)hi << 16) | lo;
      }

    f32x4 a2[4] = {zz, zz, zz, zz};
#pragma unroll
    for (int sub = 0; sub < 2; ++sub) {
      const u32* rp = &hstage[wave][fr][(sub * 32 + kg * 8) ^ ((fr & 7) << 3)];
      const uint4 q0 = *(const uint4*)rp;
      const uint4 q1 = *(const uint4*)(rp + 4);
      uint4 ah, al;
      ah.x = __builtin_amdgcn_perm(q0.y, q0.x, 0x07060302u); al.x = __builtin_amdgcn_perm(q0.y, q0.x, 0x05040100u);
      ah.y = __builtin_amdgcn_perm(q0.w, q0.z, 0x07060302u); al.y = __builtin_amdgcn_perm(q0.w, q0.z, 0x05040100u);
      ah.z = __builtin_amdgcn_perm(q1.y, q1.x, 0x07060302u); al.z = __builtin_amdgcn_perm(q1.y, q1.x, 0x05040100u);
      ah.w = __builtin_amdgcn_perm(q1.w, q1.z, 0x07060302u); al.w = __builtin_amdgcn_perm(q1.w, q1.z, 0x05040100u);
#pragma unroll
      for (int fj = 0; fj < 4; ++fj) {
        a2[fj] = mfma16(ah, w2Bh[fj][sub], a2[fj]);
        a2[fj] = mfma16(ah, w2Bl[fj][sub], a2[fj]);
        a2[fj] = mfma16(al, w2Bh[fj][sub], a2[fj]);
      }
    }

#pragma unroll
    for (int fj = 0; fj < 4; ++fj)
#pragma unroll
      for (int r = 0; r < 4; ++r) {
        float z = a2[fj][r] * s2v[fj] + t2v[fj];
        z = fmaxf(z, 0.2f * z);
        xm[fj][r] = fmaxf(xm[fj][r], z);
      }
  }

#pragma unroll
  for (int fj = 0; fj < 4; ++fj)
#pragma unroll
    for (int r = 0; r < 4; ++r) {
      const size_t e = (size_t)(pbase + kg * 4 + r) * 64 + fj * 16 + fr;
      const float v = xm[fj][r];
      const ushort_t hi = f2bf(v);
      x1o[e] = hi;
      x1o[X1_PO + e] = f2bf(v - bf2f(hi));
    }
}

// ---------------- weight prep: fold w3 + split weights (l1w: tail cols only) ----------------
__global__ __launch_bounds__(256) void prep_kernel(const float* __restrict__ w3, const float* __restrict__ w4,
    const float* __restrict__ l1w, const float* __restrict__ l2w, const float* __restrict__ w2,
    ushort_t* __restrict__ w3fp, ushort_t* __restrict__ w4p,
    ushort_t* __restrict__ l1wp, ushort_t* __restrict__ l2wp, ushort_t* __restrict__ w2p) {
  const int i = blockIdx.x * 256 + threadIdx.x;  // 0 .. 405503
  float f; ushort_t* hp; int n, j;
  if (i < 8192) {
    const int o = i >> 6, c = i & 63;
    f = w3[o * 128 + c] + w3[o * 128 + 64 + c];
    hp = w3fp; n = 8192; j = i;
  } else if (i < 8192 + 32768) {
    j = i - 8192; f = w4[j]; hp = w4p; n = 32768;
  } else if (i < 8192 + 32768 + 131072) {
    j = i - 8192 - 32768; f = l2w[j]; hp = l2wp; n = 131072;
  } else if (i < 172032 + 229376) {
    j = i - 172032;
    const int row = j / 448, col = j - row * 448;
    f = l1w[row * 1472 + 1024 + col];
    hp = l1wp; n = 229376;
  } else if (i < 401408 + 4096) {
    j = i - 401408; f = w2[j]; hp = w2p; n = 4096;
  } else return;
  const unsigned short h = f2bf(f);
  hp[j] = h;
  hp[n + j] = f2bf(f - bf2f(h));
}

// ---------------- split-bf16 MFMA GEMM ----------------
// MODE 1: gather concat [x3(256)|x2(128)|x1(64)], Ktot=448; epilogue adds per-batch yb.
template <int MODE, int OUTF32>
__global__ __launch_bounds__(256) void gemm_bf16(
    const ushort_t* __restrict__ A, const ushort_t* __restrict__ W, void* __restrict__ outv,
    const int Ktot, const int Nout, const int n_tiles,
    const int aPO, const int wPO, const int outPO,
    const float* __restrict__ gg, const float* __restrict__ bb,
    const float* __restrict__ linb, const int do_lrelu,
    const float* __restrict__ ybp, const ushort_t* __restrict__ x3,
    const ushort_t* __restrict__ x2, const ushort_t* __restrict__ x1) {
  __shared__ __align__(16) ushort_t lds[32768];
  const int tid = threadIdx.x, lane = tid & 63, wid = tid >> 6;
  const int nwg = gridDim.x;
  int id = (blockIdx.x & 7) * (nwg >> 3) + (blockIdx.x >> 3);
  const int mt = id / n_tiles, nt = id - mt * n_tiles;
  const int m0 = mt * 128, o0 = nt * 128;
  const int fr = lane & 15, kg = lane >> 4;
  const int wr = wid >> 1, wc = wid & 1;
  const int srow = lane >> 3, sslot = lane & 7;
  int rA[4], rB[4];
#pragma unroll
  for (int i = 0; i < 4; ++i) { rA[i] = wr * 64 + i * 16 + fr; rB[i] = wc * 64 + i * 16 + fr; }
  f32x4 acc[4][4] = {};
  const ushort_t* srcB = (wid == 2) ? W : W + wPO;
  const ushort_t* srcA0 = (MODE == 0) ? ((wid == 0) ? A : A + aPO) : nullptr;
  const int pl = (wid == 1);

  for (int kc = 0; kc < Ktot; kc += 64) {
#pragma unroll
    for (int c = 0; c < 16; ++c) {
      const int row = c * 8 + srow;
      const int rslot = sslot ^ (row & 7);
      const int k = kc + rslot * 8;
      const ushort_t* q;
      if (wid >= 2) {
        q = srcB + (size_t)(o0 + row) * Ktot + k;
      } else if (MODE == 0) {
        q = srcA0 + (size_t)(m0 + row) * Ktot + k;
      } else {
        const int m = m0 + row;
        if (k < 256)      q = x3 + pl * X3_PO + (size_t)m * 256 + k;
        else if (k < 384) q = x2 + pl * X2_PO + (size_t)m * 128 + (k - 256);
        else              q = x1 + pl * X1_PO + (size_t)m * 64 + (k - 384);
      }
      __builtin_amdgcn_global_load_lds(GLB_PTR(q), LDS_PTR(&lds[wid * 8192 + c * 512]), 16, 0, 0);
    }
    __syncthreads();
#pragma unroll
    for (int k0 = 0; k0 < 64; k0 += 32) {
      const int ks = (k0 >> 3) + kg;
      bf16x8 ah[4], al[4], bh[4], bl[4];
#pragma unroll
      for (int i = 0; i < 4; ++i) {
        const int off = rA[i] * 64 + ((ks ^ (rA[i] & 7)) << 3);
        ah[i] = *(const bf16x8*)&lds[off];
        al[i] = *(const bf16x8*)&lds[8192 + off];
      }
#pragma unroll
      for (int j = 0; j < 4; ++j) {
        const int off = rB[j] * 64 + ((ks ^ (rB[j] & 7)) << 3);
        bh[j] = *(const bf16x8*)&lds[16384 + off];
        bl[j] = *(const bf16x8*)&lds[24576 + off];
      }
#pragma unroll
      for (int i = 0; i < 4; ++i)
#pragma unroll
        for (int j = 0; j < 4; ++j) {
          acc[i][j] = __builtin_amdgcn_mfma_f32_16x16x32_bf16(ah[i], bh[j], acc[i][j], 0, 0, 0);
          acc[i][j] = __builtin_amdgcn_mfma_f32_16x16x32_bf16(ah[i], bl[j], acc[i][j], 0, 0, 0);
          acc[i][j] = __builtin_amdgcn_mfma_f32_16x16x32_bf16(al[i], bh[j], acc[i][j], 0, 0, 0);
        }
    }
    __syncthreads();
  }
  float s[4], t[4];
#pragma unroll
  for (int j = 0; j < 4; ++j) {
    const int o = o0 + wc * 64 + j * 16 + fr;
    s[j] = gg[o] * RS;
    float add = linb ? linb[o] : 0.f;
    if (MODE == 1) add += ybp[((m0 >> 12) << 9) + o];
    t[j] = bb[o] + add * s[j];
  }
#pragma unroll
  for (int i = 0; i < 4; ++i) {
#pragma unroll
    for (int j = 0; j < 4; ++j) {
      const int col = o0 + wc * 64 + j * 16 + fr;
#pragma unroll
      for (int r = 0; r < 4; ++r) {
        const int row = m0 + wr * 64 + i * 16 + kg * 4 + r;
        float z = acc[i][j][r] * s[j] + t[j];
        if (do_lrelu) z = lrelu(z);
        if (OUTF32) {
          ((float*)outv)[(size_t)row * Nout + col] = z;
        } else {
          ushort_t* oh = (ushort_t*)outv;
          const unsigned short h = f2bf(z);
          oh[(size_t)row * Nout + col] = h;
          oh[outPO + (size_t)row * Nout + col] = f2bf(z - bf2f(h));
        }
      }
    }
  }
}

// ---------------- max over N (partial, 8 segments); x3 is bf16 hi/lo ----------------
__global__ __launch_bounds__(256) void max_kernel(const ushort_t* __restrict__ x3, float* __restrict__ x4p) {
  __shared__ float red[4][64];
  const int bid = blockIdx.x;
  const int q = bid & 3, seg = (bid >> 2) & 7, b = bid >> 5;
  const int cl = threadIdx.x & 63, nl = threadIdx.x >> 6;
  const int c = (q << 6) + cl;
  float acc = -3.4e38f;
  const int n0 = seg * 512;
  for (int n = n0 + nl; n < n0 + 512; n += 4) {
    const size_t e = ((size_t)b * 4096 + n) * 256 + c;
    acc = fmaxf(acc, bf2f(x3[e]) + bf2f(x3[X3_PO + e]));
  }
  red[nl][cl] = acc;
  __syncthreads();
  if (threadIdx.x < 64) {
    x4p[((size_t)b * 8 + seg) * 256 + c] = fmaxf(fmaxf(red[0][cl], red[1][cl]), fmaxf(red[2][cl], red[3][cl]));
  }
}

// ---------------- x4 = max over 8 segments (8 blocks) ----------------
__global__ __launch_bounds__(256) void x4_kernel(const float* __restrict__ x4p, float* __restrict__ x4f) {
  const int b = blockIdx.x, c = threadIdx.x;
  float v = x4p[(size_t)b * 2048 + c];
#pragma unroll
  for (int s = 1; s < 8; ++s) v = fmaxf(v, x4p[(size_t)b * 2048 + s * 256 + c]);
  x4f[b * 256 + c] = v;
}

// ---------------- xg = lrelu(bn(x4 @ w5^T)); one wave per output ----------------
__global__ __launch_bounds__(256) void xg_kernel(const float* __restrict__ x4f, const float* __restrict__ w5,
    const float* __restrict__ g5, const float* __restrict__ b5, float* __restrict__ xgf) {
  const int lane = threadIdx.x & 63, wave = threadIdx.x >> 6;
  const int o = blockIdx.x * 4 + wave;
  const int b = o >> 10, oc = o & 1023;
  const float4 xv = *(const float4*)&x4f[b * 256 + lane * 4];
  const float4 w = *(const float4*)&w5[(size_t)oc * 256 + lane * 4];
  float acc = xv.x * w.x + xv.y * w.y + xv.z * w.z + xv.w * w.w;
#pragma unroll
  for (int s = 1; s < 64; s <<= 1) acc += __shfl_xor(acc, s, 64);
  if (lane == 0) xgf[o] = lrelu(acc * (g5[oc] * RS) + b5[oc]);
}

// ---------------- yb[b][o] = l1w[o, :1024] . xg[b]  (f32); one wave per output ----------------
__global__ __launch_bounds__(256) void yb_kernel(const float* __restrict__ xgf, const float* __restrict__ l1w,
    float* __restrict__ yb) {
  const int lane = threadIdx.x & 63, wave = threadIdx.x >> 6;
  const int o = blockIdx.x * 4 + wave;
  const int b = o >> 9, oc = o & 511;
  float acc = 0.f;
#pragma unroll
  for (int i = 0; i < 4; ++i) {
    const int k = i * 256 + lane * 4;
    const float4 w = *(const float4*)&l1w[(size_t)oc * 1472 + k];
    const float4 g = *(const float4*)&xgf[b * 1024 + k];
    acc += w.x * g.x + w.y * g.y + w.z * g.z + w.w * g.w;
  }
#pragma unroll
  for (int s = 1; s < 64; s <<= 1) acc += __shfl_xor(acc, s, 64);
  if (lane == 0) yb[o] = acc;
}

// ---------------- final 256->2 + transpose to (B,2,N) ----------------
__global__ __launch_bounds__(256) void l3_kernel(const float* __restrict__ h6, const float* __restrict__ l3w,
    const float* __restrict__ l3b, float* __restrict__ out) {
  __shared__ float wl[512];
  const int tid = threadIdx.x;
  wl[tid] = l3w[tid]; wl[256 + tid] = l3w[256 + tid];
  __syncthreads();
  const int m = blockIdx.x * 256 + tid;
  float a0 = 0.f, a1 = 0.f;
#pragma unroll
  for (int c = 0; c < 256; c += 4) {
    const float4 h = *(const float4*)(h6 + (size_t)m * 256 + c);
    a0 += h.x * wl[c] + h.y * wl[c + 1] + h.z * wl[c + 2] + h.w * wl[c + 3];
    a1 += h.x * wl[256 + c] + h.y * wl[256 + c + 1] + h.z * wl[256 + c + 2] + h.w * wl[256 + c + 3];
  }
  const int b = m >> 12, n = m & 4095;
  out[(size_t)b * 8192 + n] = a0 + l3b[0];
  out[(size_t)b * 8192 + 4096 + n] = a1 + l3b[1];
}

extern "C" void kernel_launch(void* const* d_in, const int* in_sizes, int n_in,
                              void* d_out, int out_size, void* d_ws, size_t ws_size,
                              hipStream_t stream) {
  const float* x   = (const float*)d_in[0];
  const float* w1  = (const float*)d_in[2];
  const float* g1  = (const float*)d_in[3];
  const float* b1  = (const float*)d_in[4];
  const float* w2  = (const float*)d_in[5];
  const float* g2  = (const float*)d_in[6];
  const float* b2  = (const float*)d_in[7];
  const float* w3  = (const float*)d_in[8];
  const float* g3  = (const float*)d_in[9];
  const float* b3  = (const float*)d_in[10];
  const float* w4  = (const float*)d_in[11];
  const float* g4  = (const float*)d_in[12];
  const float* b4  = (const float*)d_in[13];
  const float* w5  = (const float*)d_in[14];
  const float* g5  = (const float*)d_in[15];
  const float* b5  = (const float*)d_in[16];
  const float* l1w = (const float*)d_in[17];
  const float* l1b = (const float*)d_in[18];
  const float* g6  = (const float*)d_in[19];
  const float* b6  = (const float*)d_in[20];
  const float* l2w = (const float*)d_in[21];
  const float* l2b = (const float*)d_in[22];
  const float* g7  = (const float*)d_in[23];
  const float* b7  = (const float*)d_in[24];
  const float* l3w = (const float*)d_in[25];
  const float* l3b = (const float*)d_in[26];
  float* outp = (float*)d_out;

  char* ws = (char*)d_ws;
  int*      idx  = (int*)(ws + 0);
  ushort_t* x1   = (ushort_t*)(ws + 2621440);
  ushort_t* x2   = (ushort_t*)(ws + 11010048);
  ushort_t* x3   = (ushort_t*)(ws + 27787264);
  ushort_t* w2p  = (ushort_t*)(ws + 61341696);
  float*    x4p  = (float*)(ws + 61341696);
  float*    xgf  = (float*)(ws + 61407232);
  float*    x4f  = (float*)(ws + 61440000);
  float*    ybp  = (float*)(ws + 61448192);
  ushort_t* w3fp = (ushort_t*)(ws + 61440000);
  ushort_t* w4p  = (ushort_t*)(ws + 61472768);
  ushort_t* l2wp = (ushort_t*)(ws + 61603840);
  ushort_t* l1wp = (ushort_t*)(ws + 62128128);
  ushort_t* h5   = (ushort_t*)(ws + 65142784);
  float4*   xyzw = (float4*)(ws + 132251648);
  float*    h6   = (float*)(ws + 11010048);

  xyzw_kernel<<<128, 256, 0, stream>>>(x, xyzw);
  knn_kernel<<<NPID / 4, 256, 0, stream>>>(xyzw, idx);
  prep_kernel<<<1584, 256, 0, stream>>>(w3, w4, l1w, l2w, w2, w3fp, w4p, l1wp, l2wp, w2p);
  edge_kernel<<<NPID / 64, 256, 0, stream>>>(x, idx, w1, g1, b1, w2p, g2, b2, x1);
  // x2 = lrelu(bn(x1 @ w3f^T))      M=32768 K=64  O=128
  gemm_bf16<0, 0><<<256, 256, 0, stream>>>(x1, w3fp, x2, 64, 128, 1, X1_PO, 8192, X2_PO,
                                           g3, b3, nullptr, 1, nullptr, nullptr, nullptr, nullptr);
  // x3 = lrelu(bn(x2 @ w4^T))       K=128 O=256
  gemm_bf16<0, 0><<<512, 256, 0, stream>>>(x2, w4p, x3, 128, 256, 2, X2_PO, 32768, X3_PO,
                                           g4, b4, nullptr, 1, nullptr, nullptr, nullptr, nullptr);
  max_kernel<<<256, 256, 0, stream>>>(x3, x4p);
  x4_kernel<<<8, 256, 0, stream>>>(x4p, x4f);
  xg_kernel<<<2048, 256, 0, stream>>>(x4f, w5, g5, b5, xgf);
  yb_kernel<<<1024, 256, 0, stream>>>(xgf, l1w, ybp);
  // h5 = lrelu(bn(feat @ l1w^T + l1b))  K=448 (x3|x2|x1) + yb folded into bias
  gemm_bf16<1, 0><<<1024, 256, 0, stream>>>(nullptr, l1wp, h5, 448, 512, 4, 0, 229376, 16777216,
                                            g6, b6, l1b, 1, ybp, x3, x2, x1);
  // h6 = lrelu(bn(h5 @ l2w^T + l2b))    K=512 O=256  -> f32
  gemm_bf16<0, 1><<<512, 256, 0, stream>>>(h5, l2wp, h6, 512, 256, 2, 16777216, 131072, 0,
                                           g7, b7, l2b, 1, nullptr, nullptr, nullptr, nullptr);
  l3_kernel<<<128, 256, 0, stream>>>(h6, l3w, l3b, outp);
}

// Round 9
// 273.509 us; speedup vs baseline: 1.0013x; 1.0013x over previous
//
#include <hip/hip_runtime.h>

// ColorGradientNet on MI355X — round 9: kNN barrier/occupancy restructure.
//  * 1024-thread blocks (16 waves = 16 queries); whole 64KB batch xyzw staged ONCE,
//    1 barrier/block (was 8); selection per-wave, no further sync.
//  * 72KB LDS -> 2 blocks/CU = 32 waves/CU; latency chains hide across 8 waves/SIMD.
//  * Distances/selection bit-identical (mapping m = j*64+lane).
// edge / GEMMs / xg path unchanged from round 8.
// Workspace layout (bytes):
//   idx  @ 0          : 32768*20 int32                  = 2,621,440
//   x1   @ 2621440    : 2 planes x 2,097,152 ushort     = 8,388,608
//   x2   @ 11010048   : 2 x 4,194,304 ushort            = 16,777,216
//   x3   @ 27787264   : 2 x 8,388,608 ushort            = 33,554,432
//   w2p  @ 61341696   : 2 x 4,096 ushort (overlays x4p; live [prep,edge])
//   x4p  @ 61341696   : 8*8*256 f32 (live [max,x4])
//   xgf  @ 61407232   : 8*1024 f32 (live [xg,yb])
//   x4f  @ 61440000   : 8*256 f32 (overlays w3fp; live [x4,xg])
//   yb   @ 61448192   : 8*512 f32 (live [yb,l1 gemm])
//   w3f  @ 61440000   : 2 x 8,192 ushort (live [prep, x2 gemm])
//   w4p  @ 61472768   : 2 x 32,768 ushort
//   l2wp @ 61603840   : 2 x 131,072 ushort
//   l1wp @ 62128128   : 2 x 229,376 ushort (l1w tail cols 1024..1471)
//   h5   @ 65142784   : 2 x 16,777,216 ushort
//   xyzw @ 132251648  : 32768 float4                    = 524,288  (end 132,775,936)
//   h6   @ 11010048   : 32768*256 f32 (overlays x2/x3 — dead after l1 gemm)

#define KNN 20
#define NPID 32768
#define RS 0.99999500003750f  // 1/sqrt(1+1e-5)

#define X3_PO 8388608
#define X2_PO 4194304
#define X1_PO 2097152

typedef unsigned short ushort_t;
typedef unsigned int u32;
typedef __attribute__((ext_vector_type(8))) short bf16x8;
typedef __attribute__((ext_vector_type(4))) float f32x4;

#define LDS_PTR(p) ((__attribute__((address_space(3))) void*)(p))
#define GLB_PTR(p) ((const __attribute__((address_space(1))) void*)(p))

__device__ __forceinline__ float lrelu(float z) { return z >= 0.f ? z : 0.2f * z; }
__device__ __forceinline__ unsigned short f2bf(float f) {
  unsigned int u = __float_as_uint(f);
  return (unsigned short)((u + 0x7fffu + ((u >> 16) & 1u)) >> 16);
}
__device__ __forceinline__ float bf2f(unsigned short h) { return __uint_as_float((unsigned int)h << 16); }
__device__ __forceinline__ u32 pack2(u32 e0, u32 e1) { return (e1 << 16) | (e0 & 0xffffu); }
__device__ __forceinline__ f32x4 mfma16(uint4 a, uint4 b, f32x4 c) {
  return __builtin_amdgcn_mfma_f32_16x16x32_bf16(
      __builtin_bit_cast(bf16x8, a), __builtin_bit_cast(bf16x8, b), c, 0, 0, 0);
}

// ---------------- xyzw prep: interleave [x,y,z,xx] per point (exact ref op order) ----------------
__global__ __launch_bounds__(256) void xyzw_kernel(const float* __restrict__ x, float4* __restrict__ xyzw) {
  const int i = blockIdx.x * 256 + threadIdx.x;  // 0..32767
  const int b = i >> 12, n = i & 4095;
  const float* xb = x + (size_t)b * 40960;
  const float px = xb[n], py = xb[4096 + n], pz = xb[8192 + n];
  const float xx = __fadd_rn(__fadd_rn(__fmul_rn(px, px), __fmul_rn(py, py)), __fmul_rn(pz, pz));
  float4 v; v.x = px; v.y = py; v.z = pz; v.w = xx;
  xyzw[i] = v;
}

// ---------------- kNN: whole-batch LDS tile, 16 queries/block, 1 barrier ----------------
// d[] index j -> candidate m = j*64 + lane.
__global__ __launch_bounds__(1024) void knn_kernel(const float4* __restrict__ xyzw, int* __restrict__ idxo) {
  __shared__ __align__(16) float4 pt[4096];  // 64KB: whole batch xyzw
  __shared__ float cval[16][64];
  __shared__ int cidx[16][64];
  const int tid = threadIdx.x, lane = tid & 63, wave = tid >> 6;  // wave 0..15
  const int pid = blockIdx.x * 16 + wave;
  const int b = pid >> 12, n = pid & 4095;
  const float4* xw = xyzw + ((size_t)b << 12);
  // stage 4096 f4 = 64 chunks of 1KB; each wave stages 4 chunks
#pragma unroll
  for (int r = 0; r < 4; ++r) {
    const int chunk = wave * 4 + r;
    __builtin_amdgcn_global_load_lds(GLB_PTR(xw + chunk * 64 + lane),
                                     LDS_PTR((char*)pt + chunk * 1024), 16, 0, 0);
  }
  const float4 P = xw[n];
  const float px = P.x, py = P.y, pz = P.z, xxn = P.w;
  __syncthreads();  // the only barrier
  float d[64];
  float lmax = -3.4e38f;
#pragma unroll
  for (int j = 0; j < 64; ++j) {
    const float4 Q = pt[j * 64 + lane];
    const float inner = __fadd_rn(__fadd_rn(__fmul_rn(px, Q.x), __fmul_rn(py, Q.y)), __fmul_rn(pz, Q.z));
    const float pd = __fsub_rn(__fsub_rn(__fmul_rn(2.0f, inner), xxn), Q.w);
    d[j] = pd;
    lmax = fmaxf(lmax, pd);
  }
  // bitonic sort of the 64 lane maxima, descending (value only)
  float v = lmax;
#pragma unroll
  for (int k = 2; k <= 64; k <<= 1) {
#pragma unroll
    for (int j = k >> 1; j > 0; j >>= 1) {
      const float ov = __shfl_xor(v, j, 64);
      const bool keepMax = (((lane & k) == 0) == ((lane & j) == 0));
      v = keepMax ? fmaxf(v, ov) : fminf(v, ov);
    }
  }
  const float t0 = __shfl(v, 19, 64);  // lower bound on true 20th-largest
  // ballot-compact candidates >= t0 (j-major, lane-asc: deterministic)
  int base = 0;
#pragma unroll
  for (int j = 0; j < 64; ++j) {
    const bool take = (d[j] >= t0);
    const unsigned long long mk = __ballot(take);
    if (take) {
      const int pos = base + __popcll(mk & ((1ull << lane) - 1ull));
      if (pos < 64) {
        cval[wave][pos] = d[j];
        cidx[wave][pos] = (j << 6) + lane;
      }
    }
    base += (int)__popcll(mk);
  }
  const int C = base;  // wave-uniform
  int* out = idxo + (size_t)pid * KNN;
  if (C <= 64) {
    unsigned long long key = 0ull;
    if (lane < C) {
      const unsigned int u = __float_as_uint(cval[wave][lane]);
      const unsigned int ou = (u & 0x80000000u) ? ~u : (u | 0x80000000u);
      key = ((unsigned long long)ou << 32) | (unsigned long long)(0xFFFFFFFFu - (unsigned int)cidx[wave][lane]);
    }
#pragma unroll
    for (int k = 2; k <= 64; k <<= 1) {
#pragma unroll
      for (int j = k >> 1; j > 0; j >>= 1) {
        const unsigned long long ok = (unsigned long long)__shfl_xor((long long)key, j, 64);
        const bool keepMax = (((lane & k) == 0) == ((lane & j) == 0));
        const bool gt = key > ok;
        key = (keepMax == gt) ? key : ok;
      }
    }
    if (lane < KNN) out[lane] = (int)(0xFFFFFFFFu - (unsigned int)key);
  } else {
    // exact fallback (statistically never taken)
    unsigned long long used = 0ull;
#pragma unroll 1
    for (int it = 0; it < KNN; ++it) {
      float lv = -3.4e38f;
      int li = 1 << 30;
#pragma unroll
      for (int j = 0; j < 64; ++j) {
        if (!((used >> j) & 1ull) && d[j] > lv) {
          lv = d[j];
          li = (j << 6) + lane;
        }
      }
      float bv = lv;
      int bi = li;
#pragma unroll
      for (int s = 1; s < 64; s <<= 1) {
        const float ovv = __shfl_xor(bv, s, 64);
        const int oii = __shfl_xor(bi, s, 64);
        if (ovv > bv || (ovv == bv && oii < bi)) { bv = ovv; bi = oii; }
      }
      if (lane == 0) out[it] = bi;
      if ((bi & 63) == lane) used |= 1ull << (bi >> 6);
    }
  }
}

// ---------------- edge: fused MFMA h1(9->64) + h2(64->64) + max over k ----------------
__global__ __launch_bounds__(256) void edge_kernel(const float* __restrict__ x, const int* __restrict__ idxi,
    const float* __restrict__ w1, const float* __restrict__ g1, const float* __restrict__ b1,
    const ushort_t* __restrict__ w2p, const float* __restrict__ g2, const float* __restrict__ b2,
    ushort_t* __restrict__ x1o) {
  __shared__ u32 hstage[4][16][64];
  const int tid = threadIdx.x, lane = tid & 63, wave = tid >> 6;
  const int fr = lane & 15, kg = lane >> 4;
  const int pbase = blockIdx.x * 64 + wave * 16;
  const int b = (blockIdx.x * 64) >> 12;
  const float* xq = x + (size_t)b * 40960;

  const int nA = (pbase + fr) & 4095;
  float cv[6]; ushort_t chv[6], clv[6];
#pragma unroll
  for (int j = 0; j < 6; ++j) {
    cv[j] = xq[j * 4096 + nA];
    chv[j] = f2bf(cv[j]);
    clv[j] = f2bf(cv[j] - bf2f(chv[j]));
  }
  const float crv = cv[3], cgv = cv[4], cbv = cv[5];

  u32 aC0 = 0, aC1 = 0, aC2 = 0, aC3 = 0;
  if (kg == 0) { aC0 = pack2(chv[0], chv[1]); aC1 = pack2(chv[2], chv[3]); aC2 = pack2(chv[4], chv[5]); }
  else if (kg == 1) { aC0 = (u32)chv[0] << 16; aC1 = pack2(chv[1], chv[2]); aC2 = pack2(chv[3], chv[4]); aC3 = chv[5]; }
  else if (kg == 2) { aC1 = pack2(clv[0], clv[1]); aC2 = pack2(clv[2], clv[3]); aC3 = pack2(clv[4], clv[5]); }

  float s1v[4], t1v[4], s2v[4], t2v[4];
#pragma unroll
  for (int fj = 0; fj < 4; ++fj) {
    const int och = fj * 16 + fr;
    s1v[fj] = g1[och] * RS; t1v[fj] = b1[och];
    s2v[fj] = g2[och] * RS; t2v[fj] = b2[och];
  }

  uint4 w1Bv[4];
#pragma unroll
  for (int fj = 0; fj < 4; ++fj) {
    const int och = fj * 16 + fr;
    ushort_t wh[9], wl[9];
#pragma unroll
    for (int j = 0; j < 9; ++j) {
      const float wv = w1[och * 9 + j];
      wh[j] = f2bf(wv);
      wl[j] = f2bf(wv - bf2f(wh[j]));
    }
    uint4 q;
    if (kg == 0)      { q.x = pack2(wh[0], wh[1]); q.y = pack2(wh[2], wh[3]); q.z = pack2(wh[4], wh[5]); q.w = pack2(wh[6], wh[7]); }
    else if (kg == 1) { q.x = pack2(wh[8], wl[0]); q.y = pack2(wl[1], wl[2]); q.z = pack2(wl[3], wl[4]); q.w = pack2(wl[5], wl[6]); }
    else if (kg == 2) { q.x = pack2(wl[7], wl[8]); q.y = pack2(wh[0], wh[1]); q.z = pack2(wh[2], wh[3]); q.w = pack2(wh[4], wh[5]); }
    else              { q.x = pack2(wh[6], wh[7]); q.y = pack2(wh[8], 0);     q.z = 0;                   q.w = 0; }
    w1Bv[fj] = q;
  }

  uint4 w2Bh[4][2], w2Bl[4][2];
#pragma unroll
  for (int fj = 0; fj < 4; ++fj) {
    const int och = fj * 16 + fr;
#pragma unroll
    for (int sub = 0; sub < 2; ++sub) {
      const ushort_t* ph = w2p + och * 64 + sub * 32 + kg * 8;
      w2Bh[fj][sub] = *(const uint4*)ph;
      w2Bl[fj][sub] = *(const uint4*)(ph + 4096);
    }
  }

  const int prow = (pbase + fr) * KNN;
  int miA = idxi[prow];
  int miN = idxi[prow + 1];
  float pr = xq[12288 + miA], pg = xq[16384 + miA], pb = xq[20480 + miA];

  f32x4 xm[4];
#pragma unroll
  for (int fj = 0; fj < 4; ++fj) { xm[fj][0] = -3.4e38f; xm[fj][1] = -3.4e38f; xm[fj][2] = -3.4e38f; xm[fj][3] = -3.4e38f; }
  const f32x4 zz = {0.f, 0.f, 0.f, 0.f};

#pragma unroll 1
  for (int kk = 0; kk < KNN; ++kk) {
    const float nrv = pr, ngv = pg, nbv = pb;
    if (kk < KNN - 1) { pr = xq[12288 + miN]; pg = xq[16384 + miN]; pb = xq[20480 + miN]; }
    if (kk < KNN - 2) { miN = idxi[prow + kk + 2]; }

    const float dr = crv - nrv, dg = cgv - ngv, db = cbv - nbv;
    const ushort_t drh = f2bf(dr), dgh = f2bf(dg), dbh = f2bf(db);
    const ushort_t drl = f2bf(dr - bf2f(drh)), dgl = f2bf(dg - bf2f(dgh)), dbl = f2bf(db - bf2f(dbh));

    uint4 aF;
    if (kg == 0)      { aF.x = aC0; aF.y = aC1; aF.z = aC2; aF.w = pack2(drh, dgh); }
    else if (kg == 1) { aF.x = aC0 | dbh; aF.y = aC1; aF.z = aC2; aF.w = aC3 | ((u32)drh << 16); }
    else if (kg == 2) { aF.x = pack2(dgh, dbh); aF.y = aC1; aF.z = aC2; aF.w = aC3; }
    else              { aF.x = pack2(drl, dgl); aF.y = (u32)dbl; aF.z = 0; aF.w = 0; }

    f32x4 h1a[4];
#pragma unroll
    for (int fj = 0; fj < 4; ++fj) h1a[fj] = mfma16(aF, w1Bv[fj], zz);

#pragma unroll
    for (int fj = 0; fj < 4; ++fj)
#pragma unroll
      for (int r = 0; r < 4; ++r) {
        float z = h1a[fj][r] * s1v[fj] + t1v[fj];
        z = fmaxf(z, 0.2f * z);
        const ushort_t hi = f2bf(z), lo = f2bf(z - bf2f(hi));
        const int pC = kg * 4 + r;
        hstage[wave][pC][(fj * 16 + fr) ^ ((pC & 7) << 3)] = ((u32)hi << 16) | lo;
      }

    f32x4 a2[4] = {zz, zz, zz, zz};
#pragma unroll
    for (int sub = 0; sub < 2; ++sub) {
      const u32* rp = &hstage[wave][fr][(sub * 32 + kg * 8) ^ ((fr & 7) << 3)];
      const uint4 q0 = *(const uint4*)rp;
      const uint4 q1 = *(const uint4*)(rp + 4);
      uint4 ah, al;
      ah.x = __builtin_amdgcn_perm(q0.y, q0.x, 0x07060302u); al.x = __builtin_amdgcn_perm(q0.y, q0.x, 0x05040100u);
      ah.y = __builtin_amdgcn_perm(q0.w, q0.z, 0x07060302u); al.y = __builtin_amdgcn_perm(q0.w, q0.z, 0x05040100u);
      ah.z = __builtin_amdgcn_perm(q1.y, q1.x, 0x07060302u); al.z = __builtin_amdgcn_perm(q1.y, q1.x, 0x05040100u);
      ah.w = __builtin_amdgcn_perm(q1.w, q1.z, 0x07060302u); al.w = __builtin_amdgcn_perm(q1.w, q1.z, 0x05040100u);
#pragma unroll
      for (int fj = 0; fj < 4; ++fj) {
        a2[fj] = mfma16(ah, w2Bh[fj][sub], a2[fj]);
        a2[fj] = mfma16(ah, w2Bl[fj][sub], a2[fj]);
        a2[fj] = mfma16(al, w2Bh[fj][sub], a2[fj]);
      }
    }

#pragma unroll
    for (int fj = 0; fj < 4; ++fj)
#pragma unroll
      for (int r = 0; r < 4; ++r) {
        float z = a2[fj][r] * s2v[fj] + t2v[fj];
        z = fmaxf(z, 0.2f * z);
        xm[fj][r] = fmaxf(xm[fj][r], z);
      }
  }

#pragma unroll
  for (int fj = 0; fj < 4; ++fj)
#pragma unroll
    for (int r = 0; r < 4; ++r) {
      const size_t e = (size_t)(pbase + kg * 4 + r) * 64 + fj * 16 + fr;
      const float v = xm[fj][r];
      const ushort_t hi = f2bf(v);
      x1o[e] = hi;
      x1o[X1_PO + e] = f2bf(v - bf2f(hi));
    }
}

// ---------------- weight prep: fold w3 + split weights (l1w: tail cols only) ----------------
__global__ __launch_bounds__(256) void prep_kernel(const float* __restrict__ w3, const float* __restrict__ w4,
    const float* __restrict__ l1w, const float* __restrict__ l2w, const float* __restrict__ w2,
    ushort_t* __restrict__ w3fp, ushort_t* __restrict__ w4p,
    ushort_t* __restrict__ l1wp, ushort_t* __restrict__ l2wp, ushort_t* __restrict__ w2p) {
  const int i = blockIdx.x * 256 + threadIdx.x;  // 0 .. 405503
  float f; ushort_t* hp; int n, j;
  if (i < 8192) {
    const int o = i >> 6, c = i & 63;
    f = w3[o * 128 + c] + w3[o * 128 + 64 + c];
    hp = w3fp; n = 8192; j = i;
  } else if (i < 8192 + 32768) {
    j = i - 8192; f = w4[j]; hp = w4p; n = 32768;
  } else if (i < 8192 + 32768 + 131072) {
    j = i - 8192 - 32768; f = l2w[j]; hp = l2wp; n = 131072;
  } else if (i < 172032 + 229376) {
    j = i - 172032;
    const int row = j / 448, col = j - row * 448;
    f = l1w[row * 1472 + 1024 + col];
    hp = l1wp; n = 229376;
  } else if (i < 401408 + 4096) {
    j = i - 401408; f = w2[j]; hp = w2p; n = 4096;
  } else return;
  const unsigned short h = f2bf(f);
  hp[j] = h;
  hp[n + j] = f2bf(f - bf2f(h));
}

// ---------------- split-bf16 MFMA GEMM ----------------
// MODE 1: gather concat [x3(256)|x2(128)|x1(64)], Ktot=448; epilogue adds per-batch yb.
template <int MODE, int OUTF32>
__global__ __launch_bounds__(256) void gemm_bf16(
    const ushort_t* __restrict__ A, const ushort_t* __restrict__ W, void* __restrict__ outv,
    const int Ktot, const int Nout, const int n_tiles,
    const int aPO, const int wPO, const int outPO,
    const float* __restrict__ gg, const float* __restrict__ bb,
    const float* __restrict__ linb, const int do_lrelu,
    const float* __restrict__ ybp, const ushort_t* __restrict__ x3,
    const ushort_t* __restrict__ x2, const ushort_t* __restrict__ x1) {
  __shared__ __align__(16) ushort_t lds[32768];
  const int tid = threadIdx.x, lane = tid & 63, wid = tid >> 6;
  const int nwg = gridDim.x;
  int id = (blockIdx.x & 7) * (nwg >> 3) + (blockIdx.x >> 3);
  const int mt = id / n_tiles, nt = id - mt * n_tiles;
  const int m0 = mt * 128, o0 = nt * 128;
  const int fr = lane & 15, kg = lane >> 4;
  const int wr = wid >> 1, wc = wid & 1;
  const int srow = lane >> 3, sslot = lane & 7;
  int rA[4], rB[4];
#pragma unroll
  for (int i = 0; i < 4; ++i) { rA[i] = wr * 64 + i * 16 + fr; rB[i] = wc * 64 + i * 16 + fr; }
  f32x4 acc[4][4] = {};
  const ushort_t* srcB = (wid == 2) ? W : W + wPO;
  const ushort_t* srcA0 = (MODE == 0) ? ((wid == 0) ? A : A + aPO) : nullptr;
  const int pl = (wid == 1);

  for (int kc = 0; kc < Ktot; kc += 64) {
#pragma unroll
    for (int c = 0; c < 16; ++c) {
      const int row = c * 8 + srow;
      const int rslot = sslot ^ (row & 7);
      const int k = kc + rslot * 8;
      const ushort_t* q;
      if (wid >= 2) {
        q = srcB + (size_t)(o0 + row) * Ktot + k;
      } else if (MODE == 0) {
        q = srcA0 + (size_t)(m0 + row) * Ktot + k;
      } else {
        const int m = m0 + row;
        if (k < 256)      q = x3 + pl * X3_PO + (size_t)m * 256 + k;
        else if (k < 384) q = x2 + pl * X2_PO + (size_t)m * 128 + (k - 256);
        else              q = x1 + pl * X1_PO + (size_t)m * 64 + (k - 384);
      }
      __builtin_amdgcn_global_load_lds(GLB_PTR(q), LDS_PTR(&lds[wid * 8192 + c * 512]), 16, 0, 0);
    }
    __syncthreads();
#pragma unroll
    for (int k0 = 0; k0 < 64; k0 += 32) {
      const int ks = (k0 >> 3) + kg;
      bf16x8 ah[4], al[4], bh[4], bl[4];
#pragma unroll
      for (int i = 0; i < 4; ++i) {
        const int off = rA[i] * 64 + ((ks ^ (rA[i] & 7)) << 3);
        ah[i] = *(const bf16x8*)&lds[off];
        al[i] = *(const bf16x8*)&lds[8192 + off];
      }
#pragma unroll
      for (int j = 0; j < 4; ++j) {
        const int off = rB[j] * 64 + ((ks ^ (rB[j] & 7)) << 3);
        bh[j] = *(const bf16x8*)&lds[16384 + off];
        bl[j] = *(const bf16x8*)&lds[24576 + off];
      }
#pragma unroll
      for (int i = 0; i < 4; ++i)
#pragma unroll
        for (int j = 0; j < 4; ++j) {
          acc[i][j] = __builtin_amdgcn_mfma_f32_16x16x32_bf16(ah[i], bh[j], acc[i][j], 0, 0, 0);
          acc[i][j] = __builtin_amdgcn_mfma_f32_16x16x32_bf16(ah[i], bl[j], acc[i][j], 0, 0, 0);
          acc[i][j] = __builtin_amdgcn_mfma_f32_16x16x32_bf16(al[i], bh[j], acc[i][j], 0, 0, 0);
        }
    }
    __syncthreads();
  }
  float s[4], t[4];
#pragma unroll
  for (int j = 0; j < 4; ++j) {
    const int o = o0 + wc * 64 + j * 16 + fr;
    s[j] = gg[o] * RS;
    float add = linb ? linb[o] : 0.f;
    if (MODE == 1) add += ybp[((m0 >> 12) << 9) + o];
    t[j] = bb[o] + add * s[j];
  }
#pragma unroll
  for (int i = 0; i < 4; ++i) {
#pragma unroll
    for (int j = 0; j < 4; ++j) {
      const int col = o0 + wc * 64 + j * 16 + fr;
#pragma unroll
      for (int r = 0; r < 4; ++r) {
        const int row = m0 + wr * 64 + i * 16 + kg * 4 + r;
        float z = acc[i][j][r] * s[j] + t[j];
        if (do_lrelu) z = lrelu(z);
        if (OUTF32) {
          ((float*)outv)[(size_t)row * Nout + col] = z;
        } else {
          ushort_t* oh = (ushort_t*)outv;
          const unsigned short h = f2bf(z);
          oh[(size_t)row * Nout + col] = h;
          oh[outPO + (size_t)row * Nout + col] = f2bf(z - bf2f(h));
        }
      }
    }
  }
}

// ---------------- max over N (partial, 8 segments); x3 is bf16 hi/lo ----------------
__global__ __launch_bounds__(256) void max_kernel(const ushort_t* __restrict__ x3, float* __restrict__ x4p) {
  __shared__ float red[4][64];
  const int bid = blockIdx.x;
  const int q = bid & 3, seg = (bid >> 2) & 7, b = bid >> 5;
  const int cl = threadIdx.x & 63, nl = threadIdx.x >> 6;
  const int c = (q << 6) + cl;
  float acc = -3.4e38f;
  const int n0 = seg * 512;
  for (int n = n0 + nl; n < n0 + 512; n += 4) {
    const size_t e = ((size_t)b * 4096 + n) * 256 + c;
    acc = fmaxf(acc, bf2f(x3[e]) + bf2f(x3[X3_PO + e]));
  }
  red[nl][cl] = acc;
  __syncthreads();
  if (threadIdx.x < 64) {
    x4p[((size_t)b * 8 + seg) * 256 + c] = fmaxf(fmaxf(red[0][cl], red[1][cl]), fmaxf(red[2][cl], red[3][cl]));
  }
}

// ---------------- x4 = max over 8 segments (8 blocks) ----------------
__global__ __launch_bounds__(256) void x4_kernel(const float* __restrict__ x4p, float* __restrict__ x4f) {
  const int b = blockIdx.x, c = threadIdx.x;
  float v = x4p[(size_t)b * 2048 + c];
#pragma unroll
  for (int s = 1; s < 8; ++s) v = fmaxf(v, x4p[(size_t)b * 2048 + s * 256 + c]);
  x4f[b * 256 + c] = v;
}

// ---------------- xg = lrelu(bn(x4 @ w5^T)); one wave per output ----------------
__global__ __launch_bounds__(256) void xg_kernel(const float* __restrict__ x4f, const float* __restrict__ w5,
    const float* __restrict__ g5, const float* __restrict__ b5, float* __restrict__ xgf) {
  const int lane = threadIdx.x & 63, wave = threadIdx.x >> 6;
  const int o = blockIdx.x * 4 + wave;
  const int b = o >> 10, oc = o & 1023;
  const float4 xv = *(const float4*)&x4f[b * 256 + lane * 4];
  const float4 w = *(const float4*)&w5[(size_t)oc * 256 + lane * 4];
  float acc = xv.x * w.x + xv.y * w.y + xv.z * w.z + xv.w * w.w;
#pragma unroll
  for (int s = 1; s < 64; s <<= 1) acc += __shfl_xor(acc, s, 64);
  if (lane == 0) xgf[o] = lrelu(acc * (g5[oc] * RS) + b5[oc]);
}

// ---------------- yb[b][o] = l1w[o, :1024] . xg[b]  (f32); one wave per output ----------------
__global__ __launch_bounds__(256) void yb_kernel(const float* __restrict__ xgf, const float* __restrict__ l1w,
    float* __restrict__ yb) {
  const int lane = threadIdx.x & 63, wave = threadIdx.x >> 6;
  const int o = blockIdx.x * 4 + wave;
  const int b = o >> 9, oc = o & 511;
  float acc = 0.f;
#pragma unroll
  for (int i = 0; i < 4; ++i) {
    const int k = i * 256 + lane * 4;
    const float4 w = *(const float4*)&l1w[(size_t)oc * 1472 + k];
    const float4 g = *(const float4*)&xgf[b * 1024 + k];
    acc += w.x * g.x + w.y * g.y + w.z * g.z + w.w * g.w;
  }
#pragma unroll
  for (int s = 1; s < 64; s <<= 1) acc += __shfl_xor(acc, s, 64);
  if (lane == 0) yb[o] = acc;
}

// ---------------- final 256->2 + transpose to (B,2,N) ----------------
__global__ __launch_bounds__(256) void l3_kernel(const float* __restrict__ h6, const float* __restrict__ l3w,
    const float* __restrict__ l3b, float* __restrict__ out) {
  __shared__ float wl[512];
  const int tid = threadIdx.x;
  wl[tid] = l3w[tid]; wl[256 + tid] = l3w[256 + tid];
  __syncthreads();
  const int m = blockIdx.x * 256 + tid;
  float a0 = 0.f, a1 = 0.f;
#pragma unroll
  for (int c = 0; c < 256; c += 4) {
    const float4 h = *(const float4*)(h6 + (size_t)m * 256 + c);
    a0 += h.x * wl[c] + h.y * wl[c + 1] + h.z * wl[c + 2] + h.w * wl[c + 3];
    a1 += h.x * wl[256 + c] + h.y * wl[256 + c + 1] + h.z * wl[256 + c + 2] + h.w * wl[256 + c + 3];
  }
  const int b = m >> 12, n = m & 4095;
  out[(size_t)b * 8192 + n] = a0 + l3b[0];
  out[(size_t)b * 8192 + 4096 + n] = a1 + l3b[1];
}

extern "C" void kernel_launch(void* const* d_in, const int* in_sizes, int n_in,
                              void* d_out, int out_size, void* d_ws, size_t ws_size,
                              hipStream_t stream) {
  const float* x   = (const float*)d_in[0];
  const float* w1  = (const float*)d_in[2];
  const float* g1  = (const float*)d_in[3];
  const float* b1  = (const float*)d_in[4];
  const float* w2  = (const float*)d_in[5];
  const float* g2  = (const float*)d_in[6];
  const float* b2  = (const float*)d_in[7];
  const float* w3  = (const float*)d_in[8];
  const float* g3  = (const float*)d_in[9];
  const float* b3  = (const float*)d_in[10];
  const float* w4  = (const float*)d_in[11];
  const float* g4  = (const float*)d_in[12];
  const float* b4  = (const float*)d_in[13];
  const float* w5  = (const float*)d_in[14];
  const float* g5  = (const float*)d_in[15];
  const float* b5  = (const float*)d_in[16];
  const float* l1w = (const float*)d_in[17];
  const float* l1b = (const float*)d_in[18];
  const float* g6  = (const float*)d_in[19];
  const float* b6  = (const float*)d_in[20];
  const float* l2w = (const float*)d_in[21];
  const float* l2b = (const float*)d_in[22];
  const float* g7  = (const float*)d_in[23];
  const float* b7  = (const float*)d_in[24];
  const float* l3w = (const float*)d_in[25];
  const float* l3b = (const float*)d_in[26];
  float* outp = (float*)d_out;

  char* ws = (char*)d_ws;
  int*      idx  = (int*)(ws + 0);
  ushort_t* x1   = (ushort_t*)(ws + 2621440);
  ushort_t* x2   = (ushort_t*)(ws + 11010048);
  ushort_t* x3   = (ushort_t*)(ws + 27787264);
  ushort_t* w2p  = (ushort_t*)(ws + 61341696);
  float*    x4p  = (float*)(ws + 61341696);
  float*    xgf  = (float*)(ws + 61407232);
  float*    x4f  = (float*)(ws + 61440000);
  float*    ybp  = (float*)(ws + 61448192);
  ushort_t* w3fp = (ushort_t*)(ws + 61440000);
  ushort_t* w4p  = (ushort_t*)(ws + 61472768);
  ushort_t* l2wp = (ushort_t*)(ws + 61603840);
  ushort_t* l1wp = (ushort_t*)(ws + 62128128);
  ushort_t* h5   = (ushort_t*)(ws + 65142784);
  float4*   xyzw = (float4*)(ws + 132251648);
  float*    h6   = (float*)(ws + 11010048);

  xyzw_kernel<<<128, 256, 0, stream>>>(x, xyzw);
  knn_kernel<<<NPID / 16, 1024, 0, stream>>>(xyzw, idx);
  prep_kernel<<<1584, 256, 0, stream>>>(w3, w4, l1w, l2w, w2, w3fp, w4p, l1wp, l2wp, w2p);
  edge_kernel<<<NPID / 64, 256, 0, stream>>>(x, idx, w1, g1, b1, w2p, g2, b2, x1);
  // x2 = lrelu(bn(x1 @ w3f^T))      M=32768 K=64  O=128
  gemm_bf16<0, 0><<<256, 256, 0, stream>>>(x1, w3fp, x2, 64, 128, 1, X1_PO, 8192, X2_PO,
                                           g3, b3, nullptr, 1, nullptr, nullptr, nullptr, nullptr);
  // x3 = lrelu(bn(x2 @ w4^T))       K=128 O=256
  gemm_bf16<0, 0><<<512, 256, 0, stream>>>(x2, w4p, x3, 128, 256, 2, X2_PO, 32768, X3_PO,
                                           g4, b4, nullptr, 1, nullptr, nullptr, nullptr, nullptr);
  max_kernel<<<256, 256, 0, stream>>>(x3, x4p);
  x4_kernel<<<8, 256, 0, stream>>>(x4p, x4f);
  xg_kernel<<<2048, 256, 0, stream>>>(x4f, w5, g5, b5, xgf);
  yb_kernel<<<1024, 256, 0, stream>>>(xgf, l1w, ybp);
  // h5 = lrelu(bn(feat @ l1w^T + l1b))  K=448 (x3|x2|x1) + yb folded into bias
  gemm_bf16<1, 0><<<1024, 256, 0, stream>>>(nullptr, l1wp, h5, 448, 512, 4, 0, 229376, 16777216,
                                            g6, b6, l1b, 1, ybp, x3, x2, x1);
  // h6 = lrelu(bn(h5 @ l2w^T + l2b))    K=512 O=256  -> f32
  gemm_bf16<0, 1><<<512, 256, 0, stream>>>(h5, l2wp, h6, 512, 256, 2, 16777216, 131072, 0,
                                           g7, b7, l2b, 1, nullptr, nullptr, nullptr, nullptr);
  l3_kernel<<<128, 256, 0, stream>>>(h6, l3w, l3b, outp);
}

// Round 10
// 259.159 us; speedup vs baseline: 1.0567x; 1.0554x over previous
//
#include <hip/hip_runtime.h>

// ColorGradientNet on MI355X — round 10:
//  * GEMM BK 64->32: LDS 64->32KB/block, occupancy 8->12 waves/CU (VGPR-limited now);
//    swizzle re-derived for 64B rows (slot ^= (row>>1)&3, 2-way = free).
//  * x4 max fused into x3-gemm epilogue via deterministic u32-encoded atomicMax
//    (LDS pre-reduce -> 128 global atomics/block); max_kernel + x4_kernel dropped;
//    prep zeroes x4u; xg decodes inline. x4 now full-f32 (more accurate).
// knn / edge / xg-yb-fold unchanged from round 9.
// Workspace layout (bytes):
//   idx  @ 0          : 32768*20 int32                  = 2,621,440
//   x1   @ 2621440    : 2 planes x 2,097,152 ushort     = 8,388,608
//   x2   @ 11010048   : 2 x 4,194,304 ushort            = 16,777,216
//   x3   @ 27787264   : 2 x 8,388,608 ushort            = 33,554,432
//   w2p  @ 61341696   : 2 x 4,096 ushort (live [prep,edge])
//   x4u  @ 61358080   : 8*256 u32 (8KB; zeroed by prep, atomicMax by x3 gemm, read by xg)
//   xgf  @ 61407232   : 8*1024 f32 (live [xg,yb])
//   yb   @ 61448192   : 8*512 f32 (live [yb,l1 gemm])
//   w3f  @ 61440000   : 2 x 8,192 ushort (live [prep, x2 gemm])
//   w4p  @ 61472768   : 2 x 32,768 ushort
//   l2wp @ 61603840   : 2 x 131,072 ushort
//   l1wp @ 62128128   : 2 x 229,376 ushort (l1w tail cols 1024..1471)
//   h5   @ 65142784   : 2 x 16,777,216 ushort
//   xyzw @ 132251648  : 32768 float4                    = 524,288
//   h6   @ 11010048   : 32768*256 f32 (overlays x2/x3 — dead after l1 gemm)

#define KNN 20
#define NPID 32768
#define RS 0.99999500003750f  // 1/sqrt(1+1e-5)

#define X3_PO 8388608
#define X2_PO 4194304
#define X1_PO 2097152

typedef unsigned short ushort_t;
typedef unsigned int u32;
typedef __attribute__((ext_vector_type(8))) short bf16x8;
typedef __attribute__((ext_vector_type(4))) float f32x4;

#define LDS_PTR(p) ((__attribute__((address_space(3))) void*)(p))
#define GLB_PTR(p) ((const __attribute__((address_space(1))) void*)(p))

__device__ __forceinline__ float lrelu(float z) { return z >= 0.f ? z : 0.2f * z; }
__device__ __forceinline__ unsigned short f2bf(float f) {
  unsigned int u = __float_as_uint(f);
  return (unsigned short)((u + 0x7fffu + ((u >> 16) & 1u)) >> 16);
}
__device__ __forceinline__ float bf2f(unsigned short h) { return __uint_as_float((unsigned int)h << 16); }
__device__ __forceinline__ u32 pack2(u32 e0, u32 e1) { return (e1 << 16) | (e0 & 0xffffu); }
// order-preserving f32<->u32 (for atomicMax): enc monotone increasing in float order
__device__ __forceinline__ u32 encf(float f) {
  const u32 u = __float_as_uint(f);
  return (u >> 31) ? ~u : (u | 0x80000000u);
}
__device__ __forceinline__ float decf(u32 e) {
  return __uint_as_float((e >> 31) ? (e ^ 0x80000000u) : ~e);
}
__device__ __forceinline__ f32x4 mfma16(uint4 a, uint4 b, f32x4 c) {
  return __builtin_amdgcn_mfma_f32_16x16x32_bf16(
      __builtin_bit_cast(bf16x8, a), __builtin_bit_cast(bf16x8, b), c, 0, 0, 0);
}

// ---------------- xyzw prep: interleave [x,y,z,xx] per point (exact ref op order) ----------------
__global__ __launch_bounds__(256) void xyzw_kernel(const float* __restrict__ x, float4* __restrict__ xyzw) {
  const int i = blockIdx.x * 256 + threadIdx.x;
  const int b = i >> 12, n = i & 4095;
  const float* xb = x + (size_t)b * 40960;
  const float px = xb[n], py = xb[4096 + n], pz = xb[8192 + n];
  const float xx = __fadd_rn(__fadd_rn(__fmul_rn(px, px), __fmul_rn(py, py)), __fmul_rn(pz, pz));
  float4 v; v.x = px; v.y = py; v.z = pz; v.w = xx;
  xyzw[i] = v;
}

// ---------------- kNN: whole-batch LDS tile, 16 queries/block, 1 barrier ----------------
__global__ __launch_bounds__(1024) void knn_kernel(const float4* __restrict__ xyzw, int* __restrict__ idxo) {
  __shared__ __align__(16) float4 pt[4096];
  __shared__ float cval[16][64];
  __shared__ int cidx[16][64];
  const int tid = threadIdx.x, lane = tid & 63, wave = tid >> 6;
  const int pid = blockIdx.x * 16 + wave;
  const int b = pid >> 12, n = pid & 4095;
  const float4* xw = xyzw + ((size_t)b << 12);
#pragma unroll
  for (int r = 0; r < 4; ++r) {
    const int chunk = wave * 4 + r;
    __builtin_amdgcn_global_load_lds(GLB_PTR(xw + chunk * 64 + lane),
                                     LDS_PTR((char*)pt + chunk * 1024), 16, 0, 0);
  }
  const float4 P = xw[n];
  const float px = P.x, py = P.y, pz = P.z, xxn = P.w;
  __syncthreads();
  float d[64];
  float lmax = -3.4e38f;
#pragma unroll
  for (int j = 0; j < 64; ++j) {
    const float4 Q = pt[j * 64 + lane];
    const float inner = __fadd_rn(__fadd_rn(__fmul_rn(px, Q.x), __fmul_rn(py, Q.y)), __fmul_rn(pz, Q.z));
    const float pd = __fsub_rn(__fsub_rn(__fmul_rn(2.0f, inner), xxn), Q.w);
    d[j] = pd;
    lmax = fmaxf(lmax, pd);
  }
  float v = lmax;
#pragma unroll
  for (int k = 2; k <= 64; k <<= 1) {
#pragma unroll
    for (int j = k >> 1; j > 0; j >>= 1) {
      const float ov = __shfl_xor(v, j, 64);
      const bool keepMax = (((lane & k) == 0) == ((lane & j) == 0));
      v = keepMax ? fmaxf(v, ov) : fminf(v, ov);
    }
  }
  const float t0 = __shfl(v, 19, 64);
  int base = 0;
#pragma unroll
  for (int j = 0; j < 64; ++j) {
    const bool take = (d[j] >= t0);
    const unsigned long long mk = __ballot(take);
    if (take) {
      const int pos = base + __popcll(mk & ((1ull << lane) - 1ull));
      if (pos < 64) {
        cval[wave][pos] = d[j];
        cidx[wave][pos] = (j << 6) + lane;
      }
    }
    base += (int)__popcll(mk);
  }
  const int C = base;
  int* out = idxo + (size_t)pid * KNN;
  if (C <= 64) {
    unsigned long long key = 0ull;
    if (lane < C) {
      const unsigned int u = __float_as_uint(cval[wave][lane]);
      const unsigned int ou = (u & 0x80000000u) ? ~u : (u | 0x80000000u);
      key = ((unsigned long long)ou << 32) | (unsigned long long)(0xFFFFFFFFu - (unsigned int)cidx[wave][lane]);
    }
#pragma unroll
    for (int k = 2; k <= 64; k <<= 1) {
#pragma unroll
      for (int j = k >> 1; j > 0; j >>= 1) {
        const unsigned long long ok = (unsigned long long)__shfl_xor((long long)key, j, 64);
        const bool keepMax = (((lane & k) == 0) == ((lane & j) == 0));
        const bool gt = key > ok;
        key = (keepMax == gt) ? key : ok;
      }
    }
    if (lane < KNN) out[lane] = (int)(0xFFFFFFFFu - (unsigned int)key);
  } else {
    unsigned long long used = 0ull;
#pragma unroll 1
    for (int it = 0; it < KNN; ++it) {
      float lv = -3.4e38f;
      int li = 1 << 30;
#pragma unroll
      for (int j = 0; j < 64; ++j) {
        if (!((used >> j) & 1ull) && d[j] > lv) {
          lv = d[j];
          li = (j << 6) + lane;
        }
      }
      float bv = lv;
      int bi = li;
#pragma unroll
      for (int s = 1; s < 64; s <<= 1) {
        const float ovv = __shfl_xor(bv, s, 64);
        const int oii = __shfl_xor(bi, s, 64);
        if (ovv > bv || (ovv == bv && oii < bi)) { bv = ovv; bi = oii; }
      }
      if (lane == 0) out[it] = bi;
      if ((bi & 63) == lane) used |= 1ull << (bi >> 6);
    }
  }
}

// ---------------- edge: fused MFMA h1(9->64) + h2(64->64) + max over k ----------------
__global__ __launch_bounds__(256) void edge_kernel(const float* __restrict__ x, const int* __restrict__ idxi,
    const float* __restrict__ w1, const float* __restrict__ g1, const float* __restrict__ b1,
    const ushort_t* __restrict__ w2p, const float* __restrict__ g2, const float* __restrict__ b2,
    ushort_t* __restrict__ x1o) {
  __shared__ u32 hstage[4][16][64];
  const int tid = threadIdx.x, lane = tid & 63, wave = tid >> 6;
  const int fr = lane & 15, kg = lane >> 4;
  const int pbase = blockIdx.x * 64 + wave * 16;
  const int b = (blockIdx.x * 64) >> 12;
  const float* xq = x + (size_t)b * 40960;

  const int nA = (pbase + fr) & 4095;
  float cv[6]; ushort_t chv[6], clv[6];
#pragma unroll
  for (int j = 0; j < 6; ++j) {
    cv[j] = xq[j * 4096 + nA];
    chv[j] = f2bf(cv[j]);
    clv[j] = f2bf(cv[j] - bf2f(chv[j]));
  }
  const float crv = cv[3], cgv = cv[4], cbv = cv[5];

  u32 aC0 = 0, aC1 = 0, aC2 = 0, aC3 = 0;
  if (kg == 0) { aC0 = pack2(chv[0], chv[1]); aC1 = pack2(chv[2], chv[3]); aC2 = pack2(chv[4], chv[5]); }
  else if (kg == 1) { aC0 = (u32)chv[0] << 16; aC1 = pack2(chv[1], chv[2]); aC2 = pack2(chv[3], chv[4]); aC3 = chv[5]; }
  else if (kg == 2) { aC1 = pack2(clv[0], clv[1]); aC2 = pack2(clv[2], clv[3]); aC3 = pack2(clv[4], clv[5]); }

  float s1v[4], t1v[4], s2v[4], t2v[4];
#pragma unroll
  for (int fj = 0; fj < 4; ++fj) {
    const int och = fj * 16 + fr;
    s1v[fj] = g1[och] * RS; t1v[fj] = b1[och];
    s2v[fj] = g2[och] * RS; t2v[fj] = b2[och];
  }

  uint4 w1Bv[4];
#pragma unroll
  for (int fj = 0; fj < 4; ++fj) {
    const int och = fj * 16 + fr;
    ushort_t wh[9], wl[9];
#pragma unroll
    for (int j = 0; j < 9; ++j) {
      const float wv = w1[och * 9 + j];
      wh[j] = f2bf(wv);
      wl[j] = f2bf(wv - bf2f(wh[j]));
    }
    uint4 q;
    if (kg == 0)      { q.x = pack2(wh[0], wh[1]); q.y = pack2(wh[2], wh[3]); q.z = pack2(wh[4], wh[5]); q.w = pack2(wh[6], wh[7]); }
    else if (kg == 1) { q.x = pack2(wh[8], wl[0]); q.y = pack2(wl[1], wl[2]); q.z = pack2(wl[3], wl[4]); q.w = pack2(wl[5], wl[6]); }
    else if (kg == 2) { q.x = pack2(wl[7], wl[8]); q.y = pack2(wh[0], wh[1]); q.z = pack2(wh[2], wh[3]); q.w = pack2(wh[4], wh[5]); }
    else              { q.x = pack2(wh[6], wh[7]); q.y = pack2(wh[8], 0);     q.z = 0;                   q.w = 0; }
    w1Bv[fj] = q;
  }

  uint4 w2Bh[4][2], w2Bl[4][2];
#pragma unroll
  for (int fj = 0; fj < 4; ++fj) {
    const int och = fj * 16 + fr;
#pragma unroll
    for (int sub = 0; sub < 2; ++sub) {
      const ushort_t* ph = w2p + och * 64 + sub * 32 + kg * 8;
      w2Bh[fj][sub] = *(const uint4*)ph;
      w2Bl[fj][sub] = *(const uint4*)(ph + 4096);
    }
  }

  const int prow = (pbase + fr) * KNN;
  int miA = idxi[prow];
  int miN = idxi[prow + 1];
  float pr = xq[12288 + miA], pg = xq[16384 + miA], pb = xq[20480 + miA];

  f32x4 xm[4];
#pragma unroll
  for (int fj = 0; fj < 4; ++fj) { xm[fj][0] = -3.4e38f; xm[fj][1] = -3.4e38f; xm[fj][2] = -3.4e38f; xm[fj][3] = -3.4e38f; }
  const f32x4 zz = {0.f, 0.f, 0.f, 0.f};

#pragma unroll 1
  for (int kk = 0; kk < KNN; ++kk) {
    const float nrv = pr, ngv = pg, nbv = pb;
    if (kk < KNN - 1) { pr = xq[12288 + miN]; pg = xq[16384 + miN]; pb = xq[20480 + miN]; }
    if (kk < KNN - 2) { miN = idxi[prow + kk + 2]; }

    const float dr = crv - nrv, dg = cgv - ngv, db = cbv - nbv;
    const ushort_t drh = f2bf(dr), dgh = f2bf(dg), dbh = f2bf(db);
    const ushort_t drl = f2bf(dr - bf2f(drh)), dgl = f2bf(dg - bf2f(dgh)), dbl = f2bf(db - bf2f(dbh));

    uint4 aF;
    if (kg == 0)      { aF.x = aC0; aF.y = aC1; aF.z = aC2; aF.w = pack2(drh, dgh); }
    else if (kg == 1) { aF.x = aC0 | dbh; aF.y = aC1; aF.z = aC2; aF.w = aC3 | ((u32)drh << 16); }
    else if (kg == 2) { aF.x = pack2(dgh, dbh); aF.y = aC1; aF.z = aC2; aF.w = aC3; }
    else              { aF.x = pack2(drl, dgl); aF.y = (u32)dbl; aF.z = 0; aF.w = 0; }

    f32x4 h1a[4];
#pragma unroll
    for (int fj = 0; fj < 4; ++fj) h1a[fj] = mfma16(aF, w1Bv[fj], zz);

#pragma unroll
    for (int fj = 0; fj < 4; ++fj)
#pragma unroll
      for (int r = 0; r < 4; ++r) {
        float z = h1a[fj][r] * s1v[fj] + t1v[fj];
        z = fmaxf(z, 0.2f * z);
        const ushort_t hi = f2bf(z), lo = f2bf(z - bf2f(hi));
        const int pC = kg * 4 + r;
        hstage[wave][pC][(fj * 16 + fr) ^ ((pC & 7) << 3)] = ((u32)hi << 16) | lo;
      }

    f32x4 a2[4] = {zz, zz, zz, zz};
#pragma unroll
    for (int sub = 0; sub < 2; ++sub) {
      const u32* rp = &hstage[wave][fr][(sub * 32 + kg * 8) ^ ((fr & 7) << 3)];
      const uint4 q0 = *(const uint4*)rp;
      const uint4 q1 = *(const uint4*)(rp + 4);
      uint4 ah, al;
      ah.x = __builtin_amdgcn_perm(q0.y, q0.x, 0x07060302u); al.x = __builtin_amdgcn_perm(q0.y, q0.x, 0x05040100u);
      ah.y = __builtin_amdgcn_perm(q0.w, q0.z, 0x07060302u); al.y = __builtin_amdgcn_perm(q0.w, q0.z, 0x05040100u);
      ah.z = __builtin_amdgcn_perm(q1.y, q1.x, 0x07060302u); al.z = __builtin_amdgcn_perm(q1.y, q1.x, 0x05040100u);
      ah.w = __builtin_amdgcn_perm(q1.w, q1.z, 0x07060302u); al.w = __builtin_amdgcn_perm(q1.w, q1.z, 0x05040100u);
#pragma unroll
      for (int fj = 0; fj < 4; ++fj) {
        a2[fj] = mfma16(ah, w2Bh[fj][sub], a2[fj]);
        a2[fj] = mfma16(ah, w2Bl[fj][sub], a2[fj]);
        a2[fj] = mfma16(al, w2Bh[fj][sub], a2[fj]);
      }
    }

#pragma unroll
    for (int fj = 0; fj < 4; ++fj)
#pragma unroll
      for (int r = 0; r < 4; ++r) {
        float z = a2[fj][r] * s2v[fj] + t2v[fj];
        z = fmaxf(z, 0.2f * z);
        xm[fj][r] = fmaxf(xm[fj][r], z);
      }
  }

#pragma unroll
  for (int fj = 0; fj < 4; ++fj)
#pragma unroll
    for (int r = 0; r < 4; ++r) {
      const size_t e = (size_t)(pbase + kg * 4 + r) * 64 + fj * 16 + fr;
      const float v = xm[fj][r];
      const ushort_t hi = f2bf(v);
      x1o[e] = hi;
      x1o[X1_PO + e] = f2bf(v - bf2f(hi));
    }
}

// ---------------- weight prep + x4u zero ----------------
__global__ __launch_bounds__(256) void prep_kernel(const float* __restrict__ w3, const float* __restrict__ w4,
    const float* __restrict__ l1w, const float* __restrict__ l2w, const float* __restrict__ w2,
    ushort_t* __restrict__ w3fp, ushort_t* __restrict__ w4p,
    ushort_t* __restrict__ l1wp, ushort_t* __restrict__ l2wp, ushort_t* __restrict__ w2p,
    u32* __restrict__ x4u) {
  const int i = blockIdx.x * 256 + threadIdx.x;  // 0 .. 407551
  float f; ushort_t* hp; int n, j;
  if (i < 8192) {
    const int o = i >> 6, c = i & 63;
    f = w3[o * 128 + c] + w3[o * 128 + 64 + c];
    hp = w3fp; n = 8192; j = i;
  } else if (i < 8192 + 32768) {
    j = i - 8192; f = w4[j]; hp = w4p; n = 32768;
  } else if (i < 8192 + 32768 + 131072) {
    j = i - 8192 - 32768; f = l2w[j]; hp = l2wp; n = 131072;
  } else if (i < 172032 + 229376) {
    j = i - 172032;
    const int row = j / 448, col = j - row * 448;
    f = l1w[row * 1472 + 1024 + col];
    hp = l1wp; n = 229376;
  } else if (i < 401408 + 4096) {
    j = i - 401408; f = w2[j]; hp = w2p; n = 4096;
  } else if (i < 405504 + 2048) {
    x4u[i - 405504] = 0u;  // < enc of any finite float
    return;
  } else return;
  const unsigned short h = f2bf(f);
  hp[j] = h;
  hp[n + j] = f2bf(f - bf2f(h));
}

// ---------------- split-bf16 MFMA GEMM, BK=32 ----------------
// MODE 1: gather concat [x3(256)|x2(128)|x1(64)], epilogue adds per-batch yb.
// DOMAX: per-column block max -> LDS pre-reduce -> global atomicMax (order-independent).
template <int MODE, int OUTF32, int DOMAX>
__global__ __launch_bounds__(256) void gemm_bf16(
    const ushort_t* __restrict__ A, const ushort_t* __restrict__ W, void* __restrict__ outv,
    const int Ktot, const int Nout, const int n_tiles,
    const int aPO, const int wPO, const int outPO,
    const float* __restrict__ gg, const float* __restrict__ bb,
    const float* __restrict__ linb, const int do_lrelu,
    const float* __restrict__ ybp, const ushort_t* __restrict__ x3,
    const ushort_t* __restrict__ x2, const ushort_t* __restrict__ x1,
    u32* __restrict__ x4u) {
  __shared__ __align__(16) ushort_t lds[16384];  // 32KB: 4 planes x [128][32]
  const int tid = threadIdx.x, lane = tid & 63, wid = tid >> 6;
  const int nwg = gridDim.x;
  int id = (blockIdx.x & 7) * (nwg >> 3) + (blockIdx.x >> 3);
  const int mt = id / n_tiles, nt = id - mt * n_tiles;
  const int m0 = mt * 128, o0 = nt * 128;
  const int fr = lane & 15, kg = lane >> 4;
  const int wr = wid >> 1, wc = wid & 1;
  int rA[4], rB[4];
#pragma unroll
  for (int i = 0; i < 4; ++i) { rA[i] = wr * 64 + i * 16 + fr; rB[i] = wc * 64 + i * 16 + fr; }
  f32x4 acc[4][4] = {};
  const ushort_t* srcB = (wid == 2) ? W : W + wPO;
  const ushort_t* srcA0 = (MODE == 0) ? ((wid == 0) ? A : A + aPO) : nullptr;
  const int pl = (wid == 1);

  for (int kc = 0; kc < Ktot; kc += 32) {
    // stage: plane `wid` = [128][32] ushort (8KB) = 8 chunks x 1KB; 16 rows of 64B per chunk
#pragma unroll
    for (int c = 0; c < 8; ++c) {
      const int row = c * 16 + (lane >> 2);
      const int rslot = (lane & 3) ^ ((row >> 1) & 3);
      const int k = kc + rslot * 8;
      const ushort_t* q;
      if (wid >= 2) {
        q = srcB + (size_t)(o0 + row) * Ktot + k;
      } else if (MODE == 0) {
        q = srcA0 + (size_t)(m0 + row) * Ktot + k;
      } else {
        const int m = m0 + row;
        if (k < 256)      q = x3 + pl * X3_PO + (size_t)m * 256 + k;
        else if (k < 384) q = x2 + pl * X2_PO + (size_t)m * 128 + (k - 256);
        else              q = x1 + pl * X1_PO + (size_t)m * 64 + (k - 384);
      }
      __builtin_amdgcn_global_load_lds(GLB_PTR(q), LDS_PTR(&lds[wid * 4096 + c * 512]), 16, 0, 0);
    }
    __syncthreads();
    bf16x8 ah[4], al[4], bh[4], bl[4];
#pragma unroll
    for (int i = 0; i < 4; ++i) {
      const int off = rA[i] * 32 + ((kg ^ ((rA[i] >> 1) & 3)) << 3);
      ah[i] = *(const bf16x8*)&lds[off];
      al[i] = *(const bf16x8*)&lds[4096 + off];
    }
#pragma unroll
    for (int j = 0; j < 4; ++j) {
      const int off = rB[j] * 32 + ((kg ^ ((rB[j] >> 1) & 3)) << 3);
      bh[j] = *(const bf16x8*)&lds[8192 + off];
      bl[j] = *(const bf16x8*)&lds[12288 + off];
    }
#pragma unroll
    for (int i = 0; i < 4; ++i)
#pragma unroll
      for (int j = 0; j < 4; ++j) {
        acc[i][j] = __builtin_amdgcn_mfma_f32_16x16x32_bf16(ah[i], bh[j], acc[i][j], 0, 0, 0);
        acc[i][j] = __builtin_amdgcn_mfma_f32_16x16x32_bf16(ah[i], bl[j], acc[i][j], 0, 0, 0);
        acc[i][j] = __builtin_amdgcn_mfma_f32_16x16x32_bf16(al[i], bh[j], acc[i][j], 0, 0, 0);
      }
    __syncthreads();
  }
  float s[4], t[4];
#pragma unroll
  for (int j = 0; j < 4; ++j) {
    const int o = o0 + wc * 64 + j * 16 + fr;
    s[j] = gg[o] * RS;
    float add = linb ? linb[o] : 0.f;
    if (MODE == 1) add += ybp[((m0 >> 12) << 9) + o];
    t[j] = bb[o] + add * s[j];
  }
  float cm[4] = {-3.4e38f, -3.4e38f, -3.4e38f, -3.4e38f};
#pragma unroll
  for (int i = 0; i < 4; ++i) {
#pragma unroll
    for (int j = 0; j < 4; ++j) {
      const int col = o0 + wc * 64 + j * 16 + fr;
#pragma unroll
      for (int r = 0; r < 4; ++r) {
        const int row = m0 + wr * 64 + i * 16 + kg * 4 + r;
        float z = acc[i][j][r] * s[j] + t[j];
        if (do_lrelu) z = lrelu(z);
        if (DOMAX) cm[j] = fmaxf(cm[j], z);
        if (OUTF32) {
          ((float*)outv)[(size_t)row * Nout + col] = z;
        } else {
          ushort_t* oh = (ushort_t*)outv;
          const unsigned short h = f2bf(z);
          oh[(size_t)row * Nout + col] = h;
          oh[outPO + (size_t)row * Nout + col] = f2bf(z - bf2f(h));
        }
      }
    }
  }
  if (DOMAX) {
    __syncthreads();
    u32* mcol = (u32*)lds;  // [128] per-block column maxima (encoded)
    if (tid < 128) mcol[tid] = 0u;
    __syncthreads();
#pragma unroll
    for (int j = 0; j < 4; ++j) atomicMax(&mcol[wc * 64 + j * 16 + fr], encf(cm[j]));
    __syncthreads();
    if (tid < 128) atomicMax(&x4u[((m0 >> 12) << 8) + o0 + tid], mcol[tid]);
  }
}

// ---------------- xg = lrelu(bn(x4 @ w5^T)); decodes x4u inline ----------------
__global__ __launch_bounds__(256) void xg_kernel(const u32* __restrict__ x4u, const float* __restrict__ w5,
    const float* __restrict__ g5, const float* __restrict__ b5, float* __restrict__ xgf) {
  const int lane = threadIdx.x & 63, wave = threadIdx.x >> 6;
  const int o = blockIdx.x * 4 + wave;
  const int b = o >> 10, oc = o & 1023;
  const uint4 xu = *(const uint4*)&x4u[b * 256 + lane * 4];
  const float4 w = *(const float4*)&w5[(size_t)oc * 256 + lane * 4];
  float acc = decf(xu.x) * w.x + decf(xu.y) * w.y + decf(xu.z) * w.z + decf(xu.w) * w.w;
#pragma unroll
  for (int s = 1; s < 64; s <<= 1) acc += __shfl_xor(acc, s, 64);
  if (lane == 0) xgf[o] = lrelu(acc * (g5[oc] * RS) + b5[oc]);
}

// ---------------- yb[b][o] = l1w[o, :1024] . xg[b]  (f32) ----------------
__global__ __launch_bounds__(256) void yb_kernel(const float* __restrict__ xgf, const float* __restrict__ l1w,
    float* __restrict__ yb) {
  const int lane = threadIdx.x & 63, wave = threadIdx.x >> 6;
  const int o = blockIdx.x * 4 + wave;
  const int b = o >> 9, oc = o & 511;
  float acc = 0.f;
#pragma unroll
  for (int i = 0; i < 4; ++i) {
    const int k = i * 256 + lane * 4;
    const float4 w = *(const float4*)&l1w[(size_t)oc * 1472 + k];
    const float4 g = *(const float4*)&xgf[b * 1024 + k];
    acc += w.x * g.x + w.y * g.y + w.z * g.z + w.w * g.w;
  }
#pragma unroll
  for (int s = 1; s < 64; s <<= 1) acc += __shfl_xor(acc, s, 64);
  if (lane == 0) yb[o] = acc;
}

// ---------------- final 256->2 + transpose to (B,2,N) ----------------
__global__ __launch_bounds__(256) void l3_kernel(const float* __restrict__ h6, const float* __restrict__ l3w,
    const float* __restrict__ l3b, float* __restrict__ out) {
  __shared__ float wl[512];
  const int tid = threadIdx.x;
  wl[tid] = l3w[tid]; wl[256 + tid] = l3w[256 + tid];
  __syncthreads();
  const int m = blockIdx.x * 256 + tid;
  float a0 = 0.f, a1 = 0.f;
#pragma unroll
  for (int c = 0; c < 256; c += 4) {
    const float4 h = *(const float4*)(h6 + (size_t)m * 256 + c);
    a0 += h.x * wl[c] + h.y * wl[c + 1] + h.z * wl[c + 2] + h.w * wl[c + 3];
    a1 += h.x * wl[256 + c] + h.y * wl[256 + c + 1] + h.z * wl[256 + c + 2] + h.w * wl[256 + c + 3];
  }
  const int b = m >> 12, n = m & 4095;
  out[(size_t)b * 8192 + n] = a0 + l3b[0];
  out[(size_t)b * 8192 + 4096 + n] = a1 + l3b[1];
}

extern "C" void kernel_launch(void* const* d_in, const int* in_sizes, int n_in,
                              void* d_out, int out_size, void* d_ws, size_t ws_size,
                              hipStream_t stream) {
  const float* x   = (const float*)d_in[0];
  const float* w1  = (const float*)d_in[2];
  const float* g1  = (const float*)d_in[3];
  const float* b1  = (const float*)d_in[4];
  const float* w2  = (const float*)d_in[5];
  const float* g2  = (const float*)d_in[6];
  const float* b2  = (const float*)d_in[7];
  const float* w3  = (const float*)d_in[8];
  const float* g3  = (const float*)d_in[9];
  const float* b3  = (const float*)d_in[10];
  const float* w4  = (const float*)d_in[11];
  const float* g4  = (const float*)d_in[12];
  const float* b4  = (const float*)d_in[13];
  const float* w5  = (const float*)d_in[14];
  const float* g5  = (const float*)d_in[15];
  const float* b5  = (const float*)d_in[16];
  const float* l1w = (const float*)d_in[17];
  const float* l1b = (const float*)d_in[18];
  const float* g6  = (const float*)d_in[19];
  const float* b6  = (const float*)d_in[20];
  const float* l2w = (const float*)d_in[21];
  const float* l2b = (const float*)d_in[22];
  const float* g7  = (const float*)d_in[23];
  const float* b7  = (const float*)d_in[24];
  const float* l3w = (const float*)d_in[25];
  const float* l3b = (const float*)d_in[26];
  float* outp = (float*)d_out;

  char* ws = (char*)d_ws;
  int*      idx  = (int*)(ws + 0);
  ushort_t* x1   = (ushort_t*)(ws + 2621440);
  ushort_t* x2   = (ushort_t*)(ws + 11010048);
  ushort_t* x3   = (ushort_t*)(ws + 27787264);
  ushort_t* w2p  = (ushort_t*)(ws + 61341696);
  u32*      x4u  = (u32*)(ws + 61358080);
  float*    xgf  = (float*)(ws + 61407232);
  float*    ybp  = (float*)(ws + 61448192);
  ushort_t* w3fp = (ushort_t*)(ws + 61440000);
  ushort_t* w4p  = (ushort_t*)(ws + 61472768);
  ushort_t* l2wp = (ushort_t*)(ws + 61603840);
  ushort_t* l1wp = (ushort_t*)(ws + 62128128);
  ushort_t* h5   = (ushort_t*)(ws + 65142784);
  float4*   xyzw = (float4*)(ws + 132251648);
  float*    h6   = (float*)(ws + 11010048);

  xyzw_kernel<<<128, 256, 0, stream>>>(x, xyzw);
  knn_kernel<<<NPID / 16, 1024, 0, stream>>>(xyzw, idx);
  prep_kernel<<<1592, 256, 0, stream>>>(w3, w4, l1w, l2w, w2, w3fp, w4p, l1wp, l2wp, w2p, x4u);
  edge_kernel<<<NPID / 64, 256, 0, stream>>>(x, idx, w1, g1, b1, w2p, g2, b2, x1);
  // x2 = lrelu(bn(x1 @ w3f^T))      M=32768 K=64  O=128
  gemm_bf16<0, 0, 0><<<256, 256, 0, stream>>>(x1, w3fp, x2, 64, 128, 1, X1_PO, 8192, X2_PO,
                                              g3, b3, nullptr, 1, nullptr, nullptr, nullptr, nullptr, nullptr);
  // x3 = lrelu(bn(x2 @ w4^T))       K=128 O=256  + fused x4 atomicMax
  gemm_bf16<0, 0, 1><<<512, 256, 0, stream>>>(x2, w4p, x3, 128, 256, 2, X2_PO, 32768, X3_PO,
                                              g4, b4, nullptr, 1, nullptr, nullptr, nullptr, nullptr, x4u);
  xg_kernel<<<2048, 256, 0, stream>>>(x4u, w5, g5, b5, xgf);
  yb_kernel<<<1024, 256, 0, stream>>>(xgf, l1w, ybp);
  // h5 = lrelu(bn(feat @ l1w^T + l1b))  K=448 (x3|x2|x1) + yb folded into bias
  gemm_bf16<1, 0, 0><<<1024, 256, 0, stream>>>(nullptr, l1wp, h5, 448, 512, 4, 0, 229376, 16777216,
                                               g6, b6, l1b, 1, ybp, x3, x2, x1, nullptr);
  // h6 = lrelu(bn(h5 @ l2w^T + l2b))    K=512 O=256  -> f32
  gemm_bf16<0, 1, 0><<<512, 256, 0, stream>>>(h5, l2wp, h6, 512, 256, 2, 16777216, 131072, 0,
                                              g7, b7, l2b, 1, nullptr, nullptr, nullptr, nullptr, nullptr);
  l3_kernel<<<128, 256, 0, stream>>>(h6, l3w, l3b, outp);
}

// Round 11
// 250.843 us; speedup vs baseline: 1.0918x; 1.0332x over previous
//
#include <hip/hip_runtime.h>

// ColorGradientNet on MI355X — round 11: kNN 2-queries-per-wave (LDS-read amortization).
//  * knn was LDS-pipe-bound (64 ds_read_b128/query + sort shuffles). Each wave now
//    serves 2 queries per tile read -> distance LDS traffic halves. d[] = float2[64]
//    (128 VGPR, launch_bounds(256,3)); 32KB half-batch tile x 2 passes.
//  * Dual-half bitonic: when both queries' candidate counts <=32 (P~98%), sort A in
//    lanes 0-31 and B in lanes 32-63 with one 15-stage 32-wide sort (30 vs 84 DS ops).
//    Wave-uniform fallbacks: C<=64 full 64-sort, C>64 exact extraction (bit-exact).
// edge / GEMMs (BK=32 + fused x4 atomicMax) / xg-yb unchanged from round 10.
// Workspace layout (bytes):
//   idx  @ 0          : 32768*20 int32                  = 2,621,440
//   x1   @ 2621440    : 2 planes x 2,097,152 ushort     = 8,388,608
//   x2   @ 11010048   : 2 x 4,194,304 ushort            = 16,777,216
//   x3   @ 27787264   : 2 x 8,388,608 ushort            = 33,554,432
//   w2p  @ 61341696   : 2 x 4,096 ushort (live [prep,edge])
//   x4u  @ 61358080   : 8*256 u32 (zeroed by prep, atomicMax by x3 gemm, read by xg)
//   xgf  @ 61407232   : 8*1024 f32 (live [xg,yb])
//   yb   @ 61448192   : 8*512 f32 (live [yb,l1 gemm])
//   w3f  @ 61440000   : 2 x 8,192 ushort (live [prep, x2 gemm])
//   w4p  @ 61472768   : 2 x 32,768 ushort
//   l2wp @ 61603840   : 2 x 131,072 ushort
//   l1wp @ 62128128   : 2 x 229,376 ushort (l1w tail cols 1024..1471)
//   h5   @ 65142784   : 2 x 16,777,216 ushort
//   xyzw @ 132251648  : 32768 float4                    = 524,288
//   h6   @ 11010048   : 32768*256 f32 (overlays x2/x3 — dead after l1 gemm)

#define KNN 20
#define NPID 32768
#define RS 0.99999500003750f  // 1/sqrt(1+1e-5)

#define X3_PO 8388608
#define X2_PO 4194304
#define X1_PO 2097152

typedef unsigned short ushort_t;
typedef unsigned int u32;
typedef __attribute__((ext_vector_type(8))) short bf16x8;
typedef __attribute__((ext_vector_type(4))) float f32x4;

#define LDS_PTR(p) ((__attribute__((address_space(3))) void*)(p))
#define GLB_PTR(p) ((const __attribute__((address_space(1))) void*)(p))

__device__ __forceinline__ float lrelu(float z) { return z >= 0.f ? z : 0.2f * z; }
__device__ __forceinline__ unsigned short f2bf(float f) {
  unsigned int u = __float_as_uint(f);
  return (unsigned short)((u + 0x7fffu + ((u >> 16) & 1u)) >> 16);
}
__device__ __forceinline__ float bf2f(unsigned short h) { return __uint_as_float((unsigned int)h << 16); }
__device__ __forceinline__ u32 pack2(u32 e0, u32 e1) { return (e1 << 16) | (e0 & 0xffffu); }
__device__ __forceinline__ u32 encf(float f) {
  const u32 u = __float_as_uint(f);
  return (u >> 31) ? ~u : (u | 0x80000000u);
}
__device__ __forceinline__ float decf(u32 e) {
  return __uint_as_float((e >> 31) ? (e ^ 0x80000000u) : ~e);
}
__device__ __forceinline__ f32x4 mfma16(uint4 a, uint4 b, f32x4 c) {
  return __builtin_amdgcn_mfma_f32_16x16x32_bf16(
      __builtin_bit_cast(bf16x8, a), __builtin_bit_cast(bf16x8, b), c, 0, 0, 0);
}

// ---------------- xyzw prep: interleave [x,y,z,xx] per point (exact ref op order) ----------------
__global__ __launch_bounds__(256) void xyzw_kernel(const float* __restrict__ x, float4* __restrict__ xyzw) {
  const int i = blockIdx.x * 256 + threadIdx.x;
  const int b = i >> 12, n = i & 4095;
  const float* xb = x + (size_t)b * 40960;
  const float px = xb[n], py = xb[4096 + n], pz = xb[8192 + n];
  const float xx = __fadd_rn(__fadd_rn(__fmul_rn(px, px), __fmul_rn(py, py)), __fmul_rn(pz, pz));
  float4 v; v.x = px; v.y = py; v.z = pz; v.w = xx;
  xyzw[i] = v;
}

// ---------------- kNN: 2 queries/wave, 32KB tile x2, dual-half sort ----------------
// d[j] = {dA, dB}; candidate m = j*64 + lane (j = t*32+jj).
__global__ __launch_bounds__(256, 3) void knn_kernel(const float4* __restrict__ xyzw, int* __restrict__ idxo) {
  __shared__ __align__(16) float4 pt[2048];  // 32KB half-batch tile
  __shared__ float cval[8][64];
  __shared__ int cidx[8][64];
  const int tid = threadIdx.x, lane = tid & 63, wave = tid >> 6;  // 4 waves, 2 queries each
  const int qbase = blockIdx.x * 8 + wave * 2;
  const int b = qbase >> 12;
  const float4* xw = xyzw + ((size_t)b << 12);
  const int nA = qbase & 4095;
  const float4 PA = xw[nA];
  const float4 PB = xw[nA + 1];
  float2 d[64];
  float lmaxA = -3.4e38f, lmaxB = -3.4e38f;
#pragma unroll                    // FULL unroll: all d[] indices compile-time (rule #20)
  for (int t = 0; t < 2; ++t) {
    if (t) __syncthreads();
#pragma unroll
    for (int r = 0; r < 8; ++r) { // stage 2048 pts x 16B = 32 chunks of 1KB; 8 per wave
      const int chunk = wave * 8 + r;
      __builtin_amdgcn_global_load_lds(GLB_PTR(xw + t * 2048 + chunk * 64 + lane),
                                       LDS_PTR((char*)pt + chunk * 1024), 16, 0, 0);
    }
    __syncthreads();
#pragma unroll
    for (int jj = 0; jj < 32; ++jj) {
      const float4 Q = pt[jj * 64 + lane];   // one read serves BOTH queries
      const float iA = __fadd_rn(__fadd_rn(__fmul_rn(PA.x, Q.x), __fmul_rn(PA.y, Q.y)), __fmul_rn(PA.z, Q.z));
      const float pdA = __fsub_rn(__fsub_rn(__fmul_rn(2.0f, iA), PA.w), Q.w);
      const float iB = __fadd_rn(__fadd_rn(__fmul_rn(PB.x, Q.x), __fmul_rn(PB.y, Q.y)), __fmul_rn(PB.z, Q.z));
      const float pdB = __fsub_rn(__fsub_rn(__fmul_rn(2.0f, iB), PB.w), Q.w);
      d[t * 32 + jj].x = pdA;
      d[t * 32 + jj].y = pdB;
      lmaxA = fmaxf(lmaxA, pdA);
      lmaxB = fmaxf(lmaxB, pdB);
    }
  }
  // per-query: bitonic sort of 64 lane maxima (descending) -> t0 = 20th-largest bound
  float t0q[2];
#pragma unroll
  for (int q = 0; q < 2; ++q) {
    float v = q ? lmaxB : lmaxA;
#pragma unroll
    for (int k = 2; k <= 64; k <<= 1) {
#pragma unroll
      for (int j = k >> 1; j > 0; j >>= 1) {
        const float ov = __shfl_xor(v, j, 64);
        const bool keepMax = (((lane & k) == 0) == ((lane & j) == 0));
        v = keepMax ? fmaxf(v, ov) : fminf(v, ov);
      }
    }
    t0q[q] = __shfl(v, 19, 64);
  }
  // ballot-compact candidates >= t0 per query
  int Cq[2];
#pragma unroll
  for (int q = 0; q < 2; ++q) {
    const float t0 = t0q[q];
    int base = 0;
#pragma unroll
    for (int j = 0; j < 64; ++j) {
      const float dv = q ? d[j].y : d[j].x;
      const bool take = (dv >= t0);
      const unsigned long long mk = __ballot(take);
      if (take) {
        const int pos = base + __popcll(mk & ((1ull << lane) - 1ull));
        if (pos < 64) {
          cval[wave * 2 + q][pos] = dv;
          cidx[wave * 2 + q][pos] = (j << 6) + lane;
        }
      }
      base += (int)__popcll(mk);
    }
    Cq[q] = base;  // wave-uniform
  }
  int* outA = idxo + (size_t)qbase * KNN;
  if (Cq[0] <= 32 && Cq[1] <= 32) {
    // dual-half: A in lanes 0-31, B in lanes 32-63; one 32-wide bitonic serves both
    const int qsel = lane >> 5, c = lane & 31;
    const int row = wave * 2 + qsel;
    const int Cc = qsel ? Cq[1] : Cq[0];
    unsigned long long key = 0ull;
    if (c < Cc) {
      key = ((unsigned long long)encf(cval[row][c]) << 32) |
            (unsigned long long)(0xFFFFFFFFu - (unsigned int)cidx[row][c]);
    }
#pragma unroll
    for (int k = 2; k <= 32; k <<= 1) {
#pragma unroll
      for (int j = k >> 1; j > 0; j >>= 1) {  // masks <32: stays within each half
        const unsigned long long ok = (unsigned long long)__shfl_xor((long long)key, j, 64);
        const bool keepMax = (((c & k) == 0) == ((c & j) == 0));
        key = (keepMax == (key > ok)) ? key : ok;
      }
    }
    if (c < KNN) outA[qsel * KNN + c] = (int)(0xFFFFFFFFu - (unsigned int)key);
  } else {
#pragma unroll
    for (int q = 0; q < 2; ++q) {
      int* out = outA + q * KNN;
      const int C = Cq[q];
      if (C <= 64) {
        unsigned long long key = 0ull;
        if (lane < C) {
          key = ((unsigned long long)encf(cval[wave * 2 + q][lane]) << 32) |
                (unsigned long long)(0xFFFFFFFFu - (unsigned int)cidx[wave * 2 + q][lane]);
        }
#pragma unroll
        for (int k = 2; k <= 64; k <<= 1) {
#pragma unroll
          for (int j = k >> 1; j > 0; j >>= 1) {
            const unsigned long long ok = (unsigned long long)__shfl_xor((long long)key, j, 64);
            const bool keepMax = (((lane & k) == 0) == ((lane & j) == 0));
            key = (keepMax == (key > ok)) ? key : ok;
          }
        }
        if (lane < KNN) out[lane] = (int)(0xFFFFFFFFu - (unsigned int)key);
      } else {
        // exact fallback (statistically never taken)
        unsigned long long used = 0ull;
#pragma unroll 1
        for (int it = 0; it < KNN; ++it) {
          float lv = -3.4e38f;
          int li = 1 << 30;
#pragma unroll
          for (int j = 0; j < 64; ++j) {
            const float dv = q ? d[j].y : d[j].x;
            if (!((used >> j) & 1ull) && dv > lv) {
              lv = dv;
              li = (j << 6) + lane;
            }
          }
          float bv = lv;
          int bi = li;
#pragma unroll
          for (int s = 1; s < 64; s <<= 1) {
            const float ovv = __shfl_xor(bv, s, 64);
            const int oii = __shfl_xor(bi, s, 64);
            if (ovv > bv || (ovv == bv && oii < bi)) { bv = ovv; bi = oii; }
          }
          if (lane == 0) out[it] = bi;
          if ((bi & 63) == lane) used |= 1ull << (bi >> 6);
        }
      }
    }
  }
}

// ---------------- edge: fused MFMA h1(9->64) + h2(64->64) + max over k ----------------
__global__ __launch_bounds__(256) void edge_kernel(const float* __restrict__ x, const int* __restrict__ idxi,
    const float* __restrict__ w1, const float* __restrict__ g1, const float* __restrict__ b1,
    const ushort_t* __restrict__ w2p, const float* __restrict__ g2, const float* __restrict__ b2,
    ushort_t* __restrict__ x1o) {
  __shared__ u32 hstage[4][16][64];
  const int tid = threadIdx.x, lane = tid & 63, wave = tid >> 6;
  const int fr = lane & 15, kg = lane >> 4;
  const int pbase = blockIdx.x * 64 + wave * 16;
  const int b = (blockIdx.x * 64) >> 12;
  const float* xq = x + (size_t)b * 40960;

  const int nA = (pbase + fr) & 4095;
  float cv[6]; ushort_t chv[6], clv[6];
#pragma unroll
  for (int j = 0; j < 6; ++j) {
    cv[j] = xq[j * 4096 + nA];
    chv[j] = f2bf(cv[j]);
    clv[j] = f2bf(cv[j] - bf2f(chv[j]));
  }
  const float crv = cv[3], cgv = cv[4], cbv = cv[5];

  u32 aC0 = 0, aC1 = 0, aC2 = 0, aC3 = 0;
  if (kg == 0) { aC0 = pack2(chv[0], chv[1]); aC1 = pack2(chv[2], chv[3]); aC2 = pack2(chv[4], chv[5]); }
  else if (kg == 1) { aC0 = (u32)chv[0] << 16; aC1 = pack2(chv[1], chv[2]); aC2 = pack2(chv[3], chv[4]); aC3 = chv[5]; }
  else if (kg == 2) { aC1 = pack2(clv[0], clv[1]); aC2 = pack2(clv[2], clv[3]); aC3 = pack2(clv[4], clv[5]); }

  float s1v[4], t1v[4], s2v[4], t2v[4];
#pragma unroll
  for (int fj = 0; fj < 4; ++fj) {
    const int och = fj * 16 + fr;
    s1v[fj] = g1[och] * RS; t1v[fj] = b1[och];
    s2v[fj] = g2[och] * RS; t2v[fj] = b2[och];
  }

  uint4 w1Bv[4];
#pragma unroll
  for (int fj = 0; fj < 4; ++fj) {
    const int och = fj * 16 + fr;
    ushort_t wh[9], wl[9];
#pragma unroll
    for (int j = 0; j < 9; ++j) {
      const float wv = w1[och * 9 + j];
      wh[j] = f2bf(wv);
      wl[j] = f2bf(wv - bf2f(wh[j]));
    }
    uint4 q;
    if (kg == 0)      { q.x = pack2(wh[0], wh[1]); q.y = pack2(wh[2], wh[3]); q.z = pack2(wh[4], wh[5]); q.w = pack2(wh[6], wh[7]); }
    else if (kg == 1) { q.x = pack2(wh[8], wl[0]); q.y = pack2(wl[1], wl[2]); q.z = pack2(wl[3], wl[4]); q.w = pack2(wl[5], wl[6]); }
    else if (kg == 2) { q.x = pack2(wl[7], wl[8]); q.y = pack2(wh[0], wh[1]); q.z = pack2(wh[2], wh[3]); q.w = pack2(wh[4], wh[5]); }
    else              { q.x = pack2(wh[6], wh[7]); q.y = pack2(wh[8], 0);     q.z = 0;                   q.w = 0; }
    w1Bv[fj] = q;
  }

  uint4 w2Bh[4][2], w2Bl[4][2];
#pragma unroll
  for (int fj = 0; fj < 4; ++fj) {
    const int och = fj * 16 + fr;
#pragma unroll
    for (int sub = 0; sub < 2; ++sub) {
      const ushort_t* ph = w2p + och * 64 + sub * 32 + kg * 8;
      w2Bh[fj][sub] = *(const uint4*)ph;
      w2Bl[fj][sub] = *(const uint4*)(ph + 4096);
    }
  }

  const int prow = (pbase + fr) * KNN;
  int miA = idxi[prow];
  int miN = idxi[prow + 1];
  float pr = xq[12288 + miA], pg = xq[16384 + miA], pb = xq[20480 + miA];

  f32x4 xm[4];
#pragma unroll
  for (int fj = 0; fj < 4; ++fj) { xm[fj][0] = -3.4e38f; xm[fj][1] = -3.4e38f; xm[fj][2] = -3.4e38f; xm[fj][3] = -3.4e38f; }
  const f32x4 zz = {0.f, 0.f, 0.f, 0.f};

#pragma unroll 1
  for (int kk = 0; kk < KNN; ++kk) {
    const float nrv = pr, ngv = pg, nbv = pb;
    if (kk < KNN - 1) { pr = xq[12288 + miN]; pg = xq[16384 + miN]; pb = xq[20480 + miN]; }
    if (kk < KNN - 2) { miN = idxi[prow + kk + 2]; }

    const float dr = crv - nrv, dg = cgv - ngv, db = cbv - nbv;
    const ushort_t drh = f2bf(dr), dgh = f2bf(dg), dbh = f2bf(db);
    const ushort_t drl = f2bf(dr - bf2f(drh)), dgl = f2bf(dg - bf2f(dgh)), dbl = f2bf(db - bf2f(dbh));

    uint4 aF;
    if (kg == 0)      { aF.x = aC0; aF.y = aC1; aF.z = aC2; aF.w = pack2(drh, dgh); }
    else if (kg == 1) { aF.x = aC0 | dbh; aF.y = aC1; aF.z = aC2; aF.w = aC3 | ((u32)drh << 16); }
    else if (kg == 2) { aF.x = pack2(dgh, dbh); aF.y = aC1; aF.z = aC2; aF.w = aC3; }
    else              { aF.x = pack2(drl, dgl); aF.y = (u32)dbl; aF.z = 0; aF.w = 0; }

    f32x4 h1a[4];
#pragma unroll
    for (int fj = 0; fj < 4; ++fj) h1a[fj] = mfma16(aF, w1Bv[fj], zz);

#pragma unroll
    for (int fj = 0; fj < 4; ++fj)
#pragma unroll
      for (int r = 0; r < 4; ++r) {
        float z = h1a[fj][r] * s1v[fj] + t1v[fj];
        z = fmaxf(z, 0.2f * z);
        const ushort_t hi = f2bf(z), lo = f2bf(z - bf2f(hi));
        const int pC = kg * 4 + r;
        hstage[wave][pC][(fj * 16 + fr) ^ ((pC & 7) << 3)] = ((u32)hi << 16) | lo;
      }

    f32x4 a2[4] = {zz, zz, zz, zz};
#pragma unroll
    for (int sub = 0; sub < 2; ++sub) {
      const u32* rp = &hstage[wave][fr][(sub * 32 + kg * 8) ^ ((fr & 7) << 3)];
      const uint4 q0 = *(const uint4*)rp;
      const uint4 q1 = *(const uint4*)(rp + 4);
      uint4 ah, al;
      ah.x = __builtin_amdgcn_perm(q0.y, q0.x, 0x07060302u); al.x = __builtin_amdgcn_perm(q0.y, q0.x, 0x05040100u);
      ah.y = __builtin_amdgcn_perm(q0.w, q0.z, 0x07060302u); al.y = __builtin_amdgcn_perm(q0.w, q0.z, 0x05040100u);
      ah.z = __builtin_amdgcn_perm(q1.y, q1.x, 0x07060302u); al.z = __builtin_amdgcn_perm(q1.y, q1.x, 0x05040100u);
      ah.w = __builtin_amdgcn_perm(q1.w, q1.z, 0x07060302u); al.w = __builtin_amdgcn_perm(q1.w, q1.z, 0x05040100u);
#pragma unroll
      for (int fj = 0; fj < 4; ++fj) {
        a2[fj] = mfma16(ah, w2Bh[fj][sub], a2[fj]);
        a2[fj] = mfma16(ah, w2Bl[fj][sub], a2[fj]);
        a2[fj] = mfma16(al, w2Bh[fj][sub], a2[fj]);
      }
    }

#pragma unroll
    for (int fj = 0; fj < 4; ++fj)
#pragma unroll
      for (int r = 0; r < 4; ++r) {
        float z = a2[fj][r] * s2v[fj] + t2v[fj];
        z = fmaxf(z, 0.2f * z);
        xm[fj][r] = fmaxf(xm[fj][r], z);
      }
  }

#pragma unroll
  for (int fj = 0; fj < 4; ++fj)
#pragma unroll
    for (int r = 0; r < 4; ++r) {
      const size_t e = (size_t)(pbase + kg * 4 + r) * 64 + fj * 16 + fr;
      const float v = xm[fj][r];
      const ushort_t hi = f2bf(v);
      x1o[e] = hi;
      x1o[X1_PO + e] = f2bf(v - bf2f(hi));
    }
}

// ---------------- weight prep + x4u zero ----------------
__global__ __launch_bounds__(256) void prep_kernel(const float* __restrict__ w3, const float* __restrict__ w4,
    const float* __restrict__ l1w, const float* __restrict__ l2w, const float* __restrict__ w2,
    ushort_t* __restrict__ w3fp, ushort_t* __restrict__ w4p,
    ushort_t* __restrict__ l1wp, ushort_t* __restrict__ l2wp, ushort_t* __restrict__ w2p,
    u32* __restrict__ x4u) {
  const int i = blockIdx.x * 256 + threadIdx.x;  // 0 .. 407551
  float f; ushort_t* hp; int n, j;
  if (i < 8192) {
    const int o = i >> 6, c = i & 63;
    f = w3[o * 128 + c] + w3[o * 128 + 64 + c];
    hp = w3fp; n = 8192; j = i;
  } else if (i < 8192 + 32768) {
    j = i - 8192; f = w4[j]; hp = w4p; n = 32768;
  } else if (i < 8192 + 32768 + 131072) {
    j = i - 8192 - 32768; f = l2w[j]; hp = l2wp; n = 131072;
  } else if (i < 172032 + 229376) {
    j = i - 172032;
    const int row = j / 448, col = j - row * 448;
    f = l1w[row * 1472 + 1024 + col];
    hp = l1wp; n = 229376;
  } else if (i < 401408 + 4096) {
    j = i - 401408; f = w2[j]; hp = w2p; n = 4096;
  } else if (i < 405504 + 2048) {
    x4u[i - 405504] = 0u;
    return;
  } else return;
  const unsigned short h = f2bf(f);
  hp[j] = h;
  hp[n + j] = f2bf(f - bf2f(h));
}

// ---------------- split-bf16 MFMA GEMM, BK=32 ----------------
template <int MODE, int OUTF32, int DOMAX>
__global__ __launch_bounds__(256) void gemm_bf16(
    const ushort_t* __restrict__ A, const ushort_t* __restrict__ W, void* __restrict__ outv,
    const int Ktot, const int Nout, const int n_tiles,
    const int aPO, const int wPO, const int outPO,
    const float* __restrict__ gg, const float* __restrict__ bb,
    const float* __restrict__ linb, const int do_lrelu,
    const float* __restrict__ ybp, const ushort_t* __restrict__ x3,
    const ushort_t* __restrict__ x2, const ushort_t* __restrict__ x1,
    u32* __restrict__ x4u) {
  __shared__ __align__(16) ushort_t lds[16384];  // 32KB: 4 planes x [128][32]
  const int tid = threadIdx.x, lane = tid & 63, wid = tid >> 6;
  const int nwg = gridDim.x;
  int id = (blockIdx.x & 7) * (nwg >> 3) + (blockIdx.x >> 3);
  const int mt = id / n_tiles, nt = id - mt * n_tiles;
  const int m0 = mt * 128, o0 = nt * 128;
  const int fr = lane & 15, kg = lane >> 4;
  const int wr = wid >> 1, wc = wid & 1;
  int rA[4], rB[4];
#pragma unroll
  for (int i = 0; i < 4; ++i) { rA[i] = wr * 64 + i * 16 + fr; rB[i] = wc * 64 + i * 16 + fr; }
  f32x4 acc[4][4] = {};
  const ushort_t* srcB = (wid == 2) ? W : W + wPO;
  const ushort_t* srcA0 = (MODE == 0) ? ((wid == 0) ? A : A + aPO) : nullptr;
  const int pl = (wid == 1);

  for (int kc = 0; kc < Ktot; kc += 32) {
#pragma unroll
    for (int c = 0; c < 8; ++c) {
      const int row = c * 16 + (lane >> 2);
      const int rslot = (lane & 3) ^ ((row >> 1) & 3);
      const int k = kc + rslot * 8;
      const ushort_t* q;
      if (wid >= 2) {
        q = srcB + (size_t)(o0 + row) * Ktot + k;
      } else if (MODE == 0) {
        q = srcA0 + (size_t)(m0 + row) * Ktot + k;
      } else {
        const int m = m0 + row;
        if (k < 256)      q = x3 + pl * X3_PO + (size_t)m * 256 + k;
        else if (k < 384) q = x2 + pl * X2_PO + (size_t)m * 128 + (k - 256);
        else              q = x1 + pl * X1_PO + (size_t)m * 64 + (k - 384);
      }
      __builtin_amdgcn_global_load_lds(GLB_PTR(q), LDS_PTR(&lds[wid * 4096 + c * 512]), 16, 0, 0);
    }
    __syncthreads();
    bf16x8 ah[4], al[4], bh[4], bl[4];
#pragma unroll
    for (int i = 0; i < 4; ++i) {
      const int off = rA[i] * 32 + ((kg ^ ((rA[i] >> 1) & 3)) << 3);
      ah[i] = *(const bf16x8*)&lds[off];
      al[i] = *(const bf16x8*)&lds[4096 + off];
    }
#pragma unroll
    for (int j = 0; j < 4; ++j) {
      const int off = rB[j] * 32 + ((kg ^ ((rB[j] >> 1) & 3)) << 3);
      bh[j] = *(const bf16x8*)&lds[8192 + off];
      bl[j] = *(const bf16x8*)&lds[12288 + off];
    }
#pragma unroll
    for (int i = 0; i < 4; ++i)
#pragma unroll
      for (int j = 0; j < 4; ++j) {
        acc[i][j] = __builtin_amdgcn_mfma_f32_16x16x32_bf16(ah[i], bh[j], acc[i][j], 0, 0, 0);
        acc[i][j] = __builtin_amdgcn_mfma_f32_16x16x32_bf16(ah[i], bl[j], acc[i][j], 0, 0, 0);
        acc[i][j] = __builtin_amdgcn_mfma_f32_16x16x32_bf16(al[i], bh[j], acc[i][j], 0, 0, 0);
      }
    __syncthreads();
  }
  float s[4], t[4];
#pragma unroll
  for (int j = 0; j < 4; ++j) {
    const int o = o0 + wc * 64 + j * 16 + fr;
    s[j] = gg[o] * RS;
    float add = linb ? linb[o] : 0.f;
    if (MODE == 1) add += ybp[((m0 >> 12) << 9) + o];
    t[j] = bb[o] + add * s[j];
  }
  float cm[4] = {-3.4e38f, -3.4e38f, -3.4e38f, -3.4e38f};
#pragma unroll
  for (int i = 0; i < 4; ++i) {
#pragma unroll
    for (int j = 0; j < 4; ++j) {
      const int col = o0 + wc * 64 + j * 16 + fr;
#pragma unroll
      for (int r = 0; r < 4; ++r) {
        const int row = m0 + wr * 64 + i * 16 + kg * 4 + r;
        float z = acc[i][j][r] * s[j] + t[j];
        if (do_lrelu) z = lrelu(z);
        if (DOMAX) cm[j] = fmaxf(cm[j], z);
        if (OUTF32) {
          ((float*)outv)[(size_t)row * Nout + col] = z;
        } else {
          ushort_t* oh = (ushort_t*)outv;
          const unsigned short h = f2bf(z);
          oh[(size_t)row * Nout + col] = h;
          oh[outPO + (size_t)row * Nout + col] = f2bf(z - bf2f(h));
        }
      }
    }
  }
  if (DOMAX) {
    __syncthreads();
    u32* mcol = (u32*)lds;
    if (tid < 128) mcol[tid] = 0u;
    __syncthreads();
#pragma unroll
    for (int j = 0; j < 4; ++j) atomicMax(&mcol[wc * 64 + j * 16 + fr], encf(cm[j]));
    __syncthreads();
    if (tid < 128) atomicMax(&x4u[((m0 >> 12) << 8) + o0 + tid], mcol[tid]);
  }
}

// ---------------- xg = lrelu(bn(x4 @ w5^T)); decodes x4u inline ----------------
__global__ __launch_bounds__(256) void xg_kernel(const u32* __restrict__ x4u, const float* __restrict__ w5,
    const float* __restrict__ g5, const float* __restrict__ b5, float* __restrict__ xgf) {
  const int lane = threadIdx.x & 63, wave = threadIdx.x >> 6;
  const int o = blockIdx.x * 4 + wave;
  const int b = o >> 10, oc = o & 1023;
  const uint4 xu = *(const uint4*)&x4u[b * 256 + lane * 4];
  const float4 w = *(const float4*)&w5[(size_t)oc * 256 + lane * 4];
  float acc = decf(xu.x) * w.x + decf(xu.y) * w.y + decf(xu.z) * w.z + decf(xu.w) * w.w;
#pragma unroll
  for (int s = 1; s < 64; s <<= 1) acc += __shfl_xor(acc, s, 64);
  if (lane == 0) xgf[o] = lrelu(acc * (g5[oc] * RS) + b5[oc]);
}

// ---------------- yb[b][o] = l1w[o, :1024] . xg[b]  (f32) ----------------
__global__ __launch_bounds__(256) void yb_kernel(const float* __restrict__ xgf, const float* __restrict__ l1w,
    float* __restrict__ yb) {
  const int lane = threadIdx.x & 63, wave = threadIdx.x >> 6;
  const int o = blockIdx.x * 4 + wave;
  const int b = o >> 9, oc = o & 511;
  float acc = 0.f;
#pragma unroll
  for (int i = 0; i < 4; ++i) {
    const int k = i * 256 + lane * 4;
    const float4 w = *(const float4*)&l1w[(size_t)oc * 1472 + k];
    const float4 g = *(const float4*)&xgf[b * 1024 + k];
    acc += w.x * g.x + w.y * g.y + w.z * g.z + w.w * g.w;
  }
#pragma unroll
  for (int s = 1; s < 64; s <<= 1) acc += __shfl_xor(acc, s, 64);
  if (lane == 0) yb[o] = acc;
}

// ---------------- final 256->2 + transpose to (B,2,N) ----------------
__global__ __launch_bounds__(256) void l3_kernel(const float* __restrict__ h6, const float* __restrict__ l3w,
    const float* __restrict__ l3b, float* __restrict__ out) {
  __shared__ float wl[512];
  const int tid = threadIdx.x;
  wl[tid] = l3w[tid]; wl[256 + tid] = l3w[256 + tid];
  __syncthreads();
  const int m = blockIdx.x * 256 + tid;
  float a0 = 0.f, a1 = 0.f;
#pragma unroll
  for (int c = 0; c < 256; c += 4) {
    const float4 h = *(const float4*)(h6 + (size_t)m * 256 + c);
    a0 += h.x * wl[c] + h.y * wl[c + 1] + h.z * wl[c + 2] + h.w * wl[c + 3];
    a1 += h.x * wl[256 + c] + h.y * wl[256 + c + 1] + h.z * wl[256 + c + 2] + h.w * wl[256 + c + 3];
  }
  const int b = m >> 12, n = m & 4095;
  out[(size_t)b * 8192 + n] = a0 + l3b[0];
  out[(size_t)b * 8192 + 4096 + n] = a1 + l3b[1];
}

extern "C" void kernel_launch(void* const* d_in, const int* in_sizes, int n_in,
                              void* d_out, int out_size, void* d_ws, size_t ws_size,
                              hipStream_t stream) {
  const float* x   = (const float*)d_in[0];
  const float* w1  = (const float*)d_in[2];
  const float* g1  = (const float*)d_in[3];
  const float* b1  = (const float*)d_in[4];
  const float* w2  = (const float*)d_in[5];
  const float* g2  = (const float*)d_in[6];
  const float* b2  = (const float*)d_in[7];
  const float* w3  = (const float*)d_in[8];
  const float* g3  = (const float*)d_in[9];
  const float* b3  = (const float*)d_in[10];
  const float* w4  = (const float*)d_in[11];
  const float* g4  = (const float*)d_in[12];
  const float* b4  = (const float*)d_in[13];
  const float* w5  = (const float*)d_in[14];
  const float* g5  = (const float*)d_in[15];
  const float* b5  = (const float*)d_in[16];
  const float* l1w = (const float*)d_in[17];
  const float* l1b = (const float*)d_in[18];
  const float* g6  = (const float*)d_in[19];
  const float* b6  = (const float*)d_in[20];
  const float* l2w = (const float*)d_in[21];
  const float* l2b = (const float*)d_in[22];
  const float* g7  = (const float*)d_in[23];
  const float* b7  = (const float*)d_in[24];
  const float* l3w = (const float*)d_in[25];
  const float* l3b = (const float*)d_in[26];
  float* outp = (float*)d_out;

  char* ws = (char*)d_ws;
  int*      idx  = (int*)(ws + 0);
  ushort_t* x1   = (ushort_t*)(ws + 2621440);
  ushort_t* x2   = (ushort_t*)(ws + 11010048);
  ushort_t* x3   = (ushort_t*)(ws + 27787264);
  ushort_t* w2p  = (ushort_t*)(ws + 61341696);
  u32*      x4u  = (u32*)(ws + 61358080);
  float*    xgf  = (float*)(ws + 61407232);
  float*    ybp  = (float*)(ws + 61448192);
  ushort_t* w3fp = (ushort_t*)(ws + 61440000);
  ushort_t* w4p  = (ushort_t*)(ws + 61472768);
  ushort_t* l2wp = (ushort_t*)(ws + 61603840);
  ushort_t* l1wp = (ushort_t*)(ws + 62128128);
  ushort_t* h5   = (ushort_t*)(ws + 65142784);
  float4*   xyzw = (float4*)(ws + 132251648);
  float*    h6   = (float*)(ws + 11010048);

  xyzw_kernel<<<128, 256, 0, stream>>>(x, xyzw);
  knn_kernel<<<NPID / 8, 256, 0, stream>>>(xyzw, idx);
  prep_kernel<<<1592, 256, 0, stream>>>(w3, w4, l1w, l2w, w2, w3fp, w4p, l1wp, l2wp, w2p, x4u);
  edge_kernel<<<NPID / 64, 256, 0, stream>>>(x, idx, w1, g1, b1, w2p, g2, b2, x1);
  // x2 = lrelu(bn(x1 @ w3f^T))      M=32768 K=64  O=128
  gemm_bf16<0, 0, 0><<<256, 256, 0, stream>>>(x1, w3fp, x2, 64, 128, 1, X1_PO, 8192, X2_PO,
                                              g3, b3, nullptr, 1, nullptr, nullptr, nullptr, nullptr, nullptr);
  // x3 = lrelu(bn(x2 @ w4^T))       K=128 O=256  + fused x4 atomicMax
  gemm_bf16<0, 0, 1><<<512, 256, 0, stream>>>(x2, w4p, x3, 128, 256, 2, X2_PO, 32768, X3_PO,
                                              g4, b4, nullptr, 1, nullptr, nullptr, nullptr, nullptr, x4u);
  xg_kernel<<<2048, 256, 0, stream>>>(x4u, w5, g5, b5, xgf);
  yb_kernel<<<1024, 256, 0, stream>>>(xgf, l1w, ybp);
  // h5 = lrelu(bn(feat @ l1w^T + l1b))  K=448 (x3|x2|x1) + yb folded into bias
  gemm_bf16<1, 0, 0><<<1024, 256, 0, stream>>>(nullptr, l1wp, h5, 448, 512, 4, 0, 229376, 16777216,
                                               g6, b6, l1b, 1, ybp, x3, x2, x1, nullptr);
  // h6 = lrelu(bn(h5 @ l2w^T + l2b))    K=512 O=256  -> f32
  gemm_bf16<0, 1, 0><<<512, 256, 0, stream>>>(h5, l2wp, h6, 512, 256, 2, 16777216, 131072, 0,
                                              g7, b7, l2b, 1, nullptr, nullptr, nullptr, nullptr, nullptr);
  l3_kernel<<<128, 256, 0, stream>>>(h6, l3w, l3b, outp);
}